// Round 7
// baseline (1438.251 us; speedup 1.0000x reference)
//
#include <hip/hip_runtime.h>
#include <hip/hip_bf16.h>
#include <math.h>

// EnhancedResGCN forward. N=100000, E=1600000, IN=128, H=64, C=16, L=4.
// Round 7: (1) rank-merged CSR build (fill is atomic-free),
// (2) conv-path hw in bf16 (halves conv-gather read traffic),
// (3) BN stats fused into the conv gather (k_gather_bn).

#define EPS_BN 1e-5f

static inline int cdiv_i(int a, int b){ return (a + b - 1) / b; }

typedef __attribute__((ext_vector_type(8))) short bf16x8;
typedef __attribute__((ext_vector_type(4))) float f32x4;

__device__ inline short f2bf(float f){
  unsigned int u = __builtin_bit_cast(unsigned int, f);
  u += 0x7FFFu + ((u >> 16) & 1u);          // round-to-nearest-even
  return (short)(u >> 16);
}
__device__ inline float bf2f(unsigned short u){
  unsigned int x = ((unsigned int)u) << 16;
  return __builtin_bit_cast(float, x);
}

// ---------------- degree count + per-edge rank (merged cursor) ----------------
__global__ void k_cnt2(const int* __restrict__ src, const int* __restrict__ dst,
                       float* __restrict__ outd, int* __restrict__ cnt,
                       int* __restrict__ rank, int E){
  int e = blockIdx.x * blockDim.x + threadIdx.x;
  if (e < E){
    atomicAdd(&outd[src[e]], 1.f);
    rank[e] = atomicAdd(&cnt[dst[e]], 1);
  }
}

__global__ void k_norm2(float* __restrict__ outn, const int* __restrict__ cnt,
                        float* __restrict__ innorm, float* __restrict__ invind, int n){
  int i = blockIdx.x * blockDim.x + threadIdx.x;
  if (i < n){
    float od = fmaxf(outn[i], 1.f);
    float id = fmaxf((float)cnt[i], 1.f);
    outn[i]   = rsqrtf(od);
    innorm[i] = rsqrtf(id);
    invind[i] = 1.f / id;
  }
}

// ---------------- exclusive scan of cnt[n] -> rowptr ----------------
#define SCAN_B 256
__global__ void k_scan_a(const int* __restrict__ cnt, int* __restrict__ bsum, int n){
  __shared__ int sm[SCAN_B];
  int i = blockIdx.x * SCAN_B + threadIdx.x;
  sm[threadIdx.x] = (i < n) ? cnt[i] : 0;
  __syncthreads();
  for (int s = SCAN_B / 2; s; s >>= 1){
    if (threadIdx.x < s) sm[threadIdx.x] += sm[threadIdx.x + s];
    __syncthreads();
  }
  if (threadIdx.x == 0) bsum[blockIdx.x] = sm[0];
}

__global__ void k_scan_b(int* __restrict__ bsum, int nb, int* __restrict__ rowptr_n, int E){
  __shared__ int sm[512];
  int t = threadIdx.x;
  int orig = (t < nb) ? bsum[t] : 0;
  sm[t] = orig;
  __syncthreads();
  for (int off = 1; off < 512; off <<= 1){
    int v = (t >= off) ? sm[t - off] : 0;
    __syncthreads();
    sm[t] += v;
    __syncthreads();
  }
  if (t < nb) bsum[t] = sm[t] - orig;
  if (t == 0) *rowptr_n = E;
}

__global__ void k_scan_c(const int* __restrict__ cnt, const int* __restrict__ bsum,
                         int* __restrict__ rowptr, int n){
  __shared__ int sm[SCAN_B];
  int i = blockIdx.x * SCAN_B + threadIdx.x;
  int orig = (i < n) ? cnt[i] : 0;
  sm[threadIdx.x] = orig;
  __syncthreads();
  for (int off = 1; off < SCAN_B; off <<= 1){
    int v = (threadIdx.x >= off) ? sm[threadIdx.x - off] : 0;
    __syncthreads();
    sm[threadIdx.x] += v;
    __syncthreads();
  }
  if (i < n) rowptr[i] = sm[threadIdx.x] - orig + bsum[blockIdx.x];
}

// atomic-free fill using precomputed rank
__global__ void k_fill2(const int* __restrict__ src, const int* __restrict__ dst,
                        const int* __restrict__ rowptr, const int* __restrict__ rank,
                        int* __restrict__ csr, int E){
  int e = blockIdx.x * blockDim.x + threadIdx.x;
  if (e < E){
    csr[rowptr[dst[e]] + rank[e]] = src[e];
  }
}

// ---------------- MFMA GEMM: Y = (RS? X*rscale : X) @ W (+bias)(+=Y)(relu), OBF: bf16 out ----
template<int K, int NF, int RELU, int ACC, int RS, int OBF>
__global__ __launch_bounds__(256) void k_gemm_mfma(
    const float* __restrict__ X, const float* __restrict__ W,
    const float* __restrict__ bias, const float* __restrict__ rscale,
    float* __restrict__ Y, int n, int nout)
{
  constexpr int KSTEPS = K / 32;
  __shared__ short WP[KSTEPS * NF * 4 * 16 * 8];   // fragment-ordered bf16 W

  const int tid  = threadIdx.x;
  const int wave = tid >> 6, lane = tid & 63;
  const int lrow = lane & 15, lgrp = lane >> 4;
  const int col0 = blockIdx.y * (NF * 16);

  for (int i = tid; i < KSTEPS * NF * 4 * 16; i += 256){
    int c  = i & 15;
    int kg = (i >> 4) & 3;
    int t2 = i >> 6;
    int nf = t2 % NF, kstep = t2 / NF;
    int col = col0 + nf * 16 + c;
    short* dst8 = &WP[((kstep * NF + nf) * 4 + kg) * 128 + c * 8];
#pragma unroll
    for (int j = 0; j < 8; ++j){
      int k = kstep * 32 + kg * 8 + j;
      dst8[j] = (col < nout) ? f2bf(W[(size_t)k * nout + col]) : (short)0;
    }
  }
  __syncthreads();

  const int row = blockIdx.x * 64 + wave * 16 + lrow;
  const bool rok = (row < n);
  const float rs = (RS && rok) ? rscale[row] : 1.f;

  f32x4 acc[NF];
#pragma unroll
  for (int nf = 0; nf < NF; ++nf) acc[nf] = (f32x4){0.f, 0.f, 0.f, 0.f};

#pragma unroll
  for (int kstep = 0; kstep < KSTEPS; ++kstep){
    bf16x8 a;
    if (rok){
      const float* p = X + (size_t)row * K + kstep * 32 + lgrp * 8;
      float4 v0 = *reinterpret_cast<const float4*>(p);
      float4 v1 = *reinterpret_cast<const float4*>(p + 4);
      a[0] = f2bf(v0.x * rs); a[1] = f2bf(v0.y * rs);
      a[2] = f2bf(v0.z * rs); a[3] = f2bf(v0.w * rs);
      a[4] = f2bf(v1.x * rs); a[5] = f2bf(v1.y * rs);
      a[6] = f2bf(v1.z * rs); a[7] = f2bf(v1.w * rs);
    } else {
#pragma unroll
      for (int j = 0; j < 8; ++j) a[j] = 0;
    }
#pragma unroll
    for (int nf = 0; nf < NF; ++nf){
      bf16x8 b = *reinterpret_cast<const bf16x8*>(
          &WP[((kstep * NF + nf) * 4 + lgrp) * 128 + lrow * 8]);
      acc[nf] = __builtin_amdgcn_mfma_f32_16x16x32_bf16(a, b, acc[nf], 0, 0, 0);
    }
  }

#pragma unroll
  for (int nf = 0; nf < NF; ++nf){
    int col = col0 + nf * 16 + lrow;
    if (col >= nout) continue;
    float bv = bias ? bias[col] : 0.f;
#pragma unroll
    for (int r = 0; r < 4; ++r){
      int orow = blockIdx.x * 64 + wave * 16 + lgrp * 4 + r;
      if (orow >= n) continue;
      float v = acc[nf][r] + bv;
      size_t o = (size_t)orow * nout + col;
      if (ACC) v += Y[o];
      if (RELU) v = fmaxf(v, 0.f);
      if (OBF) ((short*)Y)[o] = f2bf(v);
      else     Y[o] = v;
    }
  }
}

// ---------------- CSR gather (fp32 input), for neighbor_mean path ----------------
__global__ void k_gather(const float* __restrict__ x, const int* __restrict__ rowptr,
                         const int* __restrict__ csr, float* __restrict__ out, int n){
  int node = blockIdx.x * 4 + (threadIdx.x >> 6);
  int f = threadIdx.x & 63;
  if (node >= n) return;
  int beg = rowptr[node], end = rowptr[node + 1];
  float a0 = 0.f, a1 = 0.f;
  int e = beg;
  for (; e + 1 < end; e += 2){
    int s0 = csr[e], s1 = csr[e + 1];
    a0 += x[(size_t)s0 * 64 + f];
    a1 += x[(size_t)s1 * 64 + f];
  }
  if (e < end) a0 += x[(size_t)csr[e] * 64 + f];
  out[(size_t)node * 64 + f] = a0 + a1;
}

// ---------------- CSR gather (bf16 input) + fused BN partial stats ----------------
__global__ void k_gather_bn(const unsigned short* __restrict__ x,
                            const int* __restrict__ rowptr, const int* __restrict__ csr,
                            const float* __restrict__ innorm, const float* __restrict__ b,
                            float* __restrict__ agg, float* __restrict__ bnsum,
                            float* __restrict__ bnsq, int n){
  __shared__ float s1[4][64], s2[4][64];
  int g = threadIdx.x >> 6, f = threadIdx.x & 63;
  float bf = b[f];
  float a1 = 0.f, a2 = 0.f;
  for (int base = blockIdx.x * 4; base < n; base += gridDim.x * 4){
    int node = base + g;
    if (node < n){
      int beg = rowptr[node], end = rowptr[node + 1];
      float p0 = 0.f, p1 = 0.f;
      int e = beg;
      for (; e + 1 < end; e += 2){
        p0 += bf2f(x[(size_t)csr[e] * 64 + f]);
        p1 += bf2f(x[(size_t)csr[e + 1] * 64 + f]);
      }
      if (e < end) p0 += bf2f(x[(size_t)csr[e] * 64 + f]);
      float aggv = p0 + p1;
      agg[(size_t)node * 64 + f] = aggv;
      float z = aggv * innorm[node] + bf;
      a1 += z; a2 += z * z;
    }
  }
  s1[g][f] = a1; s2[g][f] = a2;
  __syncthreads();
  if (threadIdx.x < 64){
    atomicAdd(&bnsum[f], s1[0][f] + s1[1][f] + s1[2][f] + s1[3][f]);
    atomicAdd(&bnsq[f],  s2[0][f] + s2[1][f] + s2[2][f] + s2[3][f]);
  }
}

__global__ void k_bnfin(const float* __restrict__ sum, const float* __restrict__ sumsq,
                        const float* __restrict__ gamma, const float* __restrict__ beta,
                        float* __restrict__ scale, float* __restrict__ shift, float inv_n){
  int f = threadIdx.x;  // 64 threads
  float mu  = sum[f] * inv_n;
  float var = sumsq[f] * inv_n - mu * mu;
  float sc  = gamma[f] * rsqrtf(var + EPS_BN);
  scale[f] = sc;
  shift[f] = beta[f] - mu * sc;
}

// ---------------- epilogue: h = relu(BN(agg*innorm+b) [+ hres]) ----------------
__global__ void k_post(const float* __restrict__ agg, const float* __restrict__ innorm,
                       const float* __restrict__ b, const float* __restrict__ scale,
                       const float* __restrict__ shift, const float* __restrict__ hres,
                       float* __restrict__ hout, int n64){
  int i = blockIdx.x * blockDim.x + threadIdx.x;
  if (i >= n64) return;
  int f = i & 63, row = i >> 6;
  float z = agg[i] * innorm[row] + b[f];
  z = z * scale[f] + shift[f];
  if (hres) z += hres[i];
  hout[i] = fmaxf(z, 0.f);
}

// ---------------- attention: a = sigmoid(v . W2 + b2); h += a * nb * invind ----------------
__global__ void k_attupd(const float* __restrict__ v, const float* __restrict__ W2,
                         const float* __restrict__ b2, const float* __restrict__ nb,
                         const float* __restrict__ invind, float* __restrict__ h, int n){
  int row = blockIdx.x * 4 + (threadIdx.x >> 6);
  int f = threadIdx.x & 63;
  if (row >= n) return;
  float s = v[(size_t)row * 64 + f] * W2[f];
#pragma unroll
  for (int off = 32; off; off >>= 1) s += __shfl_xor(s, off);
  float a = 1.f / (1.f + expf(-(s + b2[0])));
  size_t o = (size_t)row * 64 + f;
  float nbm = nb[o] * invind[row];
  h[o] += a * nbm;
}

extern "C" void kernel_launch(void* const* d_in, const int* in_sizes, int n_in,
                              void* d_out, int out_size, void* d_ws, size_t ws_size,
                              hipStream_t stream) {
  const float* features = (const float*)d_in[0];
  const int*   src      = (const int*)d_in[1];
  const int*   dst      = (const int*)d_in[2];
  const float* encW1 = (const float*)d_in[3];  const float* encb1 = (const float*)d_in[4];
  const float* encW2 = (const float*)d_in[5];  const float* encb2 = (const float*)d_in[6];
  const float* encW3 = (const float*)d_in[7];  const float* encb3 = (const float*)d_in[8];
  const float* attW1 = (const float*)d_in[9];  const float* attb1 = (const float*)d_in[10];
  const float* attW2 = (const float*)d_in[11]; const float* attb2 = (const float*)d_in[12];
  const float* W0    = (const float*)d_in[13]; const float* b0    = (const float*)d_in[14];
  const float* Wrest = (const float*)d_in[15]; const float* brest = (const float*)d_in[16];
  const float* gamma = (const float*)d_in[17]; const float* beta  = (const float*)d_in[18];
  const float* fcW   = (const float*)d_in[19]; const float* fcb   = (const float*)d_in[20];
  float* out = (float*)d_out;

  const int n = in_sizes[0] / 128;   // 100000
  const int E = in_sizes[1];         // 1600000

  // float workspace
  float* ws      = (float*)d_ws;
  float* h128    = ws;                          // N*128 f32
  float* agg     = h128;                        // alias (h128 dead after layer-0 GEMM)
  float* vbuf    = h128;                        // alias
  float* hbuf    = h128 + (size_t)n * 128;      // N*64 f32 (h)
  float* nbhw    = hbuf + (size_t)n * 64;       // N*64 f32 scratch (t2 / nb / hw_bf)
  float* outnorm = nbhw + (size_t)n * 64;
  float* innorm  = outnorm + n;
  float* invind  = innorm + n;
  float* bnsum   = invind + n;
  float* bnsq    = bnsum + 64;
  float* bnscale = bnsq + 64;
  float* bnshift = bnscale + 64;
  // int workspace (CSR)
  int* cnt    = (int*)(bnshift + 64);
  int* rowptr = cnt + n;                        // n+1
  int* csr    = rowptr + n + 1;                 // E
  int* bsum   = csr + E;                        // 512
  // aliases with sequential lifetimes
  int*   rank  = (int*)nbhw;                    // E ints, dead before encoder uses nbhw
  short* hw_bf = (short*)nbhw;                  // conv GEMM bf16 out, alive GEMM->gather only

  const int nt = cdiv_i(n, 64);
  const int nb = cdiv_i(n, SCAN_B);

  // ---- degrees, norms, CSR build ----
  hipMemsetAsync(outnorm, 0, (size_t)n * sizeof(float), stream);
  hipMemsetAsync(cnt, 0, (size_t)n * sizeof(int), stream);
  k_cnt2<<<cdiv_i(E, 256), 256, 0, stream>>>(src, dst, outnorm, cnt, rank, E);
  k_scan_a<<<nb, SCAN_B, 0, stream>>>(cnt, bsum, n);
  k_scan_b<<<1, 512, 0, stream>>>(bsum, nb, rowptr + n, E);
  k_scan_c<<<nb, SCAN_B, 0, stream>>>(cnt, bsum, rowptr, n);
  k_norm2<<<cdiv_i(n, 256), 256, 0, stream>>>(outnorm, cnt, innorm, invind, n);
  k_fill2<<<cdiv_i(E, 256), 256, 0, stream>>>(src, dst, rowptr, rank, csr, E);

  // ---- encoder MLP ----
  k_gemm_mfma<128,4,1,0,0,0><<<dim3(nt,1), 256, 0, stream>>>(features, encW1, encb1, nullptr, hbuf, n, 64);
  k_gemm_mfma<64, 2,1,0,0,0><<<dim3(nt,1), 256, 0, stream>>>(hbuf, encW2, encb2, nullptr, nbhw, n, 32);
  k_gemm_mfma<32, 4,0,0,0,0><<<dim3(nt,2), 256, 0, stream>>>(nbhw, encW3, encb3, nullptr, h128, n, 128);

  // ---- layer 0: hw_bf = bf16((h128*outnorm)@W0); agg+stats; post ----
  k_gemm_mfma<128,4,0,0,1,1><<<dim3(nt,1), 256, 0, stream>>>(h128, W0, nullptr, outnorm, (float*)hw_bf, n, 64);
  hipMemsetAsync(bnsum, 0, 128 * sizeof(float), stream);
  k_gather_bn<<<1024, 256, 0, stream>>>((const unsigned short*)hw_bf, rowptr, csr, innorm, b0, agg, bnsum, bnsq, n);
  k_bnfin<<<1, 64, 0, stream>>>(bnsum, bnsq, gamma, beta, bnscale, bnshift, 1.f / (float)n);
  k_post<<<cdiv_i(n * 64, 256), 256, 0, stream>>>(agg, innorm, b0, bnscale, bnshift, nullptr, hbuf, n * 64);

  // ---- layers 1..3 ----
  for (int i = 1; i < 4; ++i){
    const float* Wi = Wrest + (size_t)(i - 1) * 64 * 64;
    const float* bi = brest + (size_t)(i - 1) * 64;
    // neighbor sum (fp32 gather of h)
    k_gather<<<cdiv_i(n, 4), 256, 0, stream>>>(hbuf, rowptr, csr, nbhw, n);
    // attention gate
    k_gemm_mfma<64,4,0,0,0,0><<<dim3(nt,1), 256, 0, stream>>>(hbuf, attW1, attb1, nullptr, vbuf, n, 64);
    k_gemm_mfma<64,4,1,1,1,0><<<dim3(nt,1), 256, 0, stream>>>(nbhw, attW1 + 64 * 64, nullptr, invind, vbuf, n, 64);
    k_attupd<<<cdiv_i(n, 4), 256, 0, stream>>>(vbuf, attW2, attb2, nbhw, invind, hbuf, n);
    // conv: hw_bf = bf16((h*outnorm)@Wi); agg+stats; post (+res)
    k_gemm_mfma<64,4,0,0,1,1><<<dim3(nt,1), 256, 0, stream>>>(hbuf, Wi, nullptr, outnorm, (float*)hw_bf, n, 64);
    hipMemsetAsync(bnsum, 0, 128 * sizeof(float), stream);
    k_gather_bn<<<1024, 256, 0, stream>>>((const unsigned short*)hw_bf, rowptr, csr, innorm, bi, agg, bnsum, bnsq, n);
    k_bnfin<<<1, 64, 0, stream>>>(bnsum, bnsq, gamma + i * 64, beta + i * 64, bnscale, bnshift, 1.f / (float)n);
    k_post<<<cdiv_i(n * 64, 256), 256, 0, stream>>>(agg, innorm, bi, bnscale, bnshift, hbuf, hbuf, n * 64);
  }

  // ---- classifier ----
  k_gemm_mfma<64,1,0,0,0,0><<<dim3(nt,1), 256, 0, stream>>>(hbuf, fcW, fcb, nullptr, out, n, 16);
}

// Round 8
// 1249.251 us; speedup vs baseline: 1.1513x; 1.1513x over previous
//
#include <hip/hip_runtime.h>
#include <hip/hip_bf16.h>
#include <math.h>

// EnhancedResGCN forward. N=100000, E=1600000, IN=128, H=64, C=16, L=4.
// Round 8: un-fuse gather/BN (restore 25k-block gather TLP), keep rank-merged
// CSR + bf16 hw; NEW: bf16 shadow of h so nb-gathers read 128B/row.

#define EPS_BN 1e-5f

static inline int cdiv_i(int a, int b){ return (a + b - 1) / b; }

typedef __attribute__((ext_vector_type(8))) short bf16x8;
typedef __attribute__((ext_vector_type(4))) float f32x4;

__device__ inline short f2bf(float f){
  unsigned int u = __builtin_bit_cast(unsigned int, f);
  u += 0x7FFFu + ((u >> 16) & 1u);          // round-to-nearest-even
  return (short)(u >> 16);
}
__device__ inline float bf2f(unsigned short u){
  unsigned int x = ((unsigned int)u) << 16;
  return __builtin_bit_cast(float, x);
}

// ---------------- degree count + per-edge rank (merged cursor) ----------------
__global__ void k_cnt2(const int* __restrict__ src, const int* __restrict__ dst,
                       float* __restrict__ outd, int* __restrict__ cnt,
                       int* __restrict__ rank, int E){
  int e = blockIdx.x * blockDim.x + threadIdx.x;
  if (e < E){
    atomicAdd(&outd[src[e]], 1.f);
    rank[e] = atomicAdd(&cnt[dst[e]], 1);
  }
}

__global__ void k_norm2(float* __restrict__ outn, const int* __restrict__ cnt,
                        float* __restrict__ innorm, float* __restrict__ invind, int n){
  int i = blockIdx.x * blockDim.x + threadIdx.x;
  if (i < n){
    float od = fmaxf(outn[i], 1.f);
    float id = fmaxf((float)cnt[i], 1.f);
    outn[i]   = rsqrtf(od);
    innorm[i] = rsqrtf(id);
    invind[i] = 1.f / id;
  }
}

// ---------------- exclusive scan of cnt[n] -> rowptr ----------------
#define SCAN_B 256
__global__ void k_scan_a(const int* __restrict__ cnt, int* __restrict__ bsum, int n){
  __shared__ int sm[SCAN_B];
  int i = blockIdx.x * SCAN_B + threadIdx.x;
  sm[threadIdx.x] = (i < n) ? cnt[i] : 0;
  __syncthreads();
  for (int s = SCAN_B / 2; s; s >>= 1){
    if (threadIdx.x < s) sm[threadIdx.x] += sm[threadIdx.x + s];
    __syncthreads();
  }
  if (threadIdx.x == 0) bsum[blockIdx.x] = sm[0];
}

__global__ void k_scan_b(int* __restrict__ bsum, int nb, int* __restrict__ rowptr_n, int E){
  __shared__ int sm[512];
  int t = threadIdx.x;
  int orig = (t < nb) ? bsum[t] : 0;
  sm[t] = orig;
  __syncthreads();
  for (int off = 1; off < 512; off <<= 1){
    int v = (t >= off) ? sm[t - off] : 0;
    __syncthreads();
    sm[t] += v;
    __syncthreads();
  }
  if (t < nb) bsum[t] = sm[t] - orig;
  if (t == 0) *rowptr_n = E;
}

__global__ void k_scan_c(const int* __restrict__ cnt, const int* __restrict__ bsum,
                         int* __restrict__ rowptr, int n){
  __shared__ int sm[SCAN_B];
  int i = blockIdx.x * SCAN_B + threadIdx.x;
  int orig = (i < n) ? cnt[i] : 0;
  sm[threadIdx.x] = orig;
  __syncthreads();
  for (int off = 1; off < SCAN_B; off <<= 1){
    int v = (threadIdx.x >= off) ? sm[threadIdx.x - off] : 0;
    __syncthreads();
    sm[threadIdx.x] += v;
    __syncthreads();
  }
  if (i < n) rowptr[i] = sm[threadIdx.x] - orig + bsum[blockIdx.x];
}

// atomic-free fill using precomputed rank
__global__ void k_fill2(const int* __restrict__ src, const int* __restrict__ dst,
                        const int* __restrict__ rowptr, const int* __restrict__ rank,
                        int* __restrict__ csr, int E){
  int e = blockIdx.x * blockDim.x + threadIdx.x;
  if (e < E){
    csr[rowptr[dst[e]] + rank[e]] = src[e];
  }
}

// ---------------- MFMA GEMM: Y = (RS? X*rscale : X) @ W (+bias)(+=Y)(relu), OBF: bf16 out ----
template<int K, int NF, int RELU, int ACC, int RS, int OBF>
__global__ __launch_bounds__(256) void k_gemm_mfma(
    const float* __restrict__ X, const float* __restrict__ W,
    const float* __restrict__ bias, const float* __restrict__ rscale,
    float* __restrict__ Y, int n, int nout)
{
  constexpr int KSTEPS = K / 32;
  __shared__ short WP[KSTEPS * NF * 4 * 16 * 8];   // fragment-ordered bf16 W

  const int tid  = threadIdx.x;
  const int wave = tid >> 6, lane = tid & 63;
  const int lrow = lane & 15, lgrp = lane >> 4;
  const int col0 = blockIdx.y * (NF * 16);

  for (int i = tid; i < KSTEPS * NF * 4 * 16; i += 256){
    int c  = i & 15;
    int kg = (i >> 4) & 3;
    int t2 = i >> 6;
    int nf = t2 % NF, kstep = t2 / NF;
    int col = col0 + nf * 16 + c;
    short* dst8 = &WP[((kstep * NF + nf) * 4 + kg) * 128 + c * 8];
#pragma unroll
    for (int j = 0; j < 8; ++j){
      int k = kstep * 32 + kg * 8 + j;
      dst8[j] = (col < nout) ? f2bf(W[(size_t)k * nout + col]) : (short)0;
    }
  }
  __syncthreads();

  const int row = blockIdx.x * 64 + wave * 16 + lrow;
  const bool rok = (row < n);
  const float rs = (RS && rok) ? rscale[row] : 1.f;

  f32x4 acc[NF];
#pragma unroll
  for (int nf = 0; nf < NF; ++nf) acc[nf] = (f32x4){0.f, 0.f, 0.f, 0.f};

#pragma unroll
  for (int kstep = 0; kstep < KSTEPS; ++kstep){
    bf16x8 a;
    if (rok){
      const float* p = X + (size_t)row * K + kstep * 32 + lgrp * 8;
      float4 v0 = *reinterpret_cast<const float4*>(p);
      float4 v1 = *reinterpret_cast<const float4*>(p + 4);
      a[0] = f2bf(v0.x * rs); a[1] = f2bf(v0.y * rs);
      a[2] = f2bf(v0.z * rs); a[3] = f2bf(v0.w * rs);
      a[4] = f2bf(v1.x * rs); a[5] = f2bf(v1.y * rs);
      a[6] = f2bf(v1.z * rs); a[7] = f2bf(v1.w * rs);
    } else {
#pragma unroll
      for (int j = 0; j < 8; ++j) a[j] = 0;
    }
#pragma unroll
    for (int nf = 0; nf < NF; ++nf){
      bf16x8 b = *reinterpret_cast<const bf16x8*>(
          &WP[((kstep * NF + nf) * 4 + lgrp) * 128 + lrow * 8]);
      acc[nf] = __builtin_amdgcn_mfma_f32_16x16x32_bf16(a, b, acc[nf], 0, 0, 0);
    }
  }

#pragma unroll
  for (int nf = 0; nf < NF; ++nf){
    int col = col0 + nf * 16 + lrow;
    if (col >= nout) continue;
    float bv = bias ? bias[col] : 0.f;
#pragma unroll
    for (int r = 0; r < 4; ++r){
      int orow = blockIdx.x * 64 + wave * 16 + lgrp * 4 + r;
      if (orow >= n) continue;
      float v = acc[nf][r] + bv;
      size_t o = (size_t)orow * nout + col;
      if (ACC) v += Y[o];
      if (RELU) v = fmaxf(v, 0.f);
      if (OBF) ((short*)Y)[o] = f2bf(v);
      else     Y[o] = v;
    }
  }
}

// ---------------- CSR gather (bf16 rows in, fp32 out): out[d] = sum x[src] ----------------
__global__ void k_gather_bf(const unsigned short* __restrict__ x,
                            const int* __restrict__ rowptr, const int* __restrict__ csr,
                            float* __restrict__ out, int n){
  int node = blockIdx.x * 4 + (threadIdx.x >> 6);
  int f = threadIdx.x & 63;
  if (node >= n) return;
  int beg = rowptr[node], end = rowptr[node + 1];
  float a0 = 0.f, a1 = 0.f;
  int e = beg;
  for (; e + 1 < end; e += 2){
    int s0 = csr[e], s1 = csr[e + 1];
    a0 += bf2f(x[(size_t)s0 * 64 + f]);
    a1 += bf2f(x[(size_t)s1 * 64 + f]);
  }
  if (e < end) a0 += bf2f(x[(size_t)csr[e] * 64 + f]);
  out[(size_t)node * 64 + f] = a0 + a1;
}

// ---------------- BatchNorm stats over z = agg*in_norm + b ----------------
__global__ void k_bnstats(const float* __restrict__ agg, const float* __restrict__ innorm,
                          const float* __restrict__ b, float* __restrict__ sum,
                          float* __restrict__ sumsq, int n){
  __shared__ float s1[4][64], s2[4][64];
  int f = threadIdx.x & 63, g = threadIdx.x >> 6;
  float bf = b[f];
  float a1 = 0.f, a2 = 0.f;
  for (int row = blockIdx.x * 4 + g; row < n; row += gridDim.x * 4){
    float z = agg[(size_t)row * 64 + f] * innorm[row] + bf;
    a1 += z; a2 += z * z;
  }
  s1[g][f] = a1; s2[g][f] = a2;
  __syncthreads();
  if (threadIdx.x < 64){
    atomicAdd(&sum[f],   s1[0][f] + s1[1][f] + s1[2][f] + s1[3][f]);
    atomicAdd(&sumsq[f], s2[0][f] + s2[1][f] + s2[2][f] + s2[3][f]);
  }
}

__global__ void k_bnfin(const float* __restrict__ sum, const float* __restrict__ sumsq,
                        const float* __restrict__ gamma, const float* __restrict__ beta,
                        float* __restrict__ scale, float* __restrict__ shift, float inv_n){
  int f = threadIdx.x;  // 64 threads
  float mu  = sum[f] * inv_n;
  float var = sumsq[f] * inv_n - mu * mu;
  float sc  = gamma[f] * rsqrtf(var + EPS_BN);
  scale[f] = sc;
  shift[f] = beta[f] - mu * sc;
}

// ---------------- epilogue: h = relu(BN(agg*innorm+b) [+ hres]); bf16 shadow ----------------
__global__ void k_post(const float* __restrict__ agg, const float* __restrict__ innorm,
                       const float* __restrict__ b, const float* __restrict__ scale,
                       const float* __restrict__ shift, const float* __restrict__ hres,
                       float* __restrict__ hout, unsigned short* __restrict__ hbf, int n64){
  int i = blockIdx.x * blockDim.x + threadIdx.x;
  if (i >= n64) return;
  int f = i & 63, row = i >> 6;
  float z = agg[i] * innorm[row] + b[f];
  z = z * scale[f] + shift[f];
  if (hres) z += hres[i];
  float r = fmaxf(z, 0.f);
  hout[i] = r;
  if (hbf) hbf[i] = (unsigned short)f2bf(r);
}

// ---------------- attention: a = sigmoid(v . W2 + b2); h += a * nb * invind ----------------
__global__ void k_attupd(const float* __restrict__ v, const float* __restrict__ W2,
                         const float* __restrict__ b2, const float* __restrict__ nb,
                         const float* __restrict__ invind, float* __restrict__ h, int n){
  int row = blockIdx.x * 4 + (threadIdx.x >> 6);
  int f = threadIdx.x & 63;
  if (row >= n) return;
  float s = v[(size_t)row * 64 + f] * W2[f];
#pragma unroll
  for (int off = 32; off; off >>= 1) s += __shfl_xor(s, off);
  float a = 1.f / (1.f + expf(-(s + b2[0])));
  size_t o = (size_t)row * 64 + f;
  float nbm = nb[o] * invind[row];
  h[o] += a * nbm;
}

extern "C" void kernel_launch(void* const* d_in, const int* in_sizes, int n_in,
                              void* d_out, int out_size, void* d_ws, size_t ws_size,
                              hipStream_t stream) {
  const float* features = (const float*)d_in[0];
  const int*   src      = (const int*)d_in[1];
  const int*   dst      = (const int*)d_in[2];
  const float* encW1 = (const float*)d_in[3];  const float* encb1 = (const float*)d_in[4];
  const float* encW2 = (const float*)d_in[5];  const float* encb2 = (const float*)d_in[6];
  const float* encW3 = (const float*)d_in[7];  const float* encb3 = (const float*)d_in[8];
  const float* attW1 = (const float*)d_in[9];  const float* attb1 = (const float*)d_in[10];
  const float* attW2 = (const float*)d_in[11]; const float* attb2 = (const float*)d_in[12];
  const float* W0    = (const float*)d_in[13]; const float* b0    = (const float*)d_in[14];
  const float* Wrest = (const float*)d_in[15]; const float* brest = (const float*)d_in[16];
  const float* gamma = (const float*)d_in[17]; const float* beta  = (const float*)d_in[18];
  const float* fcW   = (const float*)d_in[19]; const float* fcb   = (const float*)d_in[20];
  float* out = (float*)d_out;

  const int n = in_sizes[0] / 128;   // 100000
  const int E = in_sizes[1];         // 1600000

  // float workspace
  float* ws      = (float*)d_ws;
  float* h128    = ws;                          // N*128 f32 (enc out; dead after L0 GEMM)
  float* agg     = h128;                        // alias: first N*64 of h128
  float* vbuf    = h128;                        // alias: first N*64 of h128
  unsigned short* h_bf = (unsigned short*)(h128 + (size_t)n * 64);  // second half of h128
  float* hbuf    = h128 + (size_t)n * 128;      // N*64 f32 (h)
  float* nbhw    = hbuf + (size_t)n * 64;       // N*64 f32 scratch (t2 / rank / nb / hw_bf)
  float* outnorm = nbhw + (size_t)n * 64;
  float* innorm  = outnorm + n;
  float* invind  = innorm + n;
  float* bnsum   = invind + n;
  float* bnsq    = bnsum + 64;
  float* bnscale = bnsq + 64;
  float* bnshift = bnscale + 64;
  // int workspace (CSR)
  int* cnt    = (int*)(bnshift + 64);
  int* rowptr = cnt + n;                        // n+1
  int* csr    = rowptr + n + 1;                 // E
  int* bsum   = csr + E;                        // 512
  // aliases with sequential lifetimes
  int*   rank  = (int*)nbhw;                    // E ints, dead before encoder uses nbhw
  unsigned short* hw_bf = (unsigned short*)nbhw;// conv GEMM bf16 out (GEMM->gather only)

  const int nt = cdiv_i(n, 64);
  const int nb = cdiv_i(n, SCAN_B);

  // ---- degrees, norms, CSR build ----
  hipMemsetAsync(outnorm, 0, (size_t)n * sizeof(float), stream);
  hipMemsetAsync(cnt, 0, (size_t)n * sizeof(int), stream);
  k_cnt2<<<cdiv_i(E, 256), 256, 0, stream>>>(src, dst, outnorm, cnt, rank, E);
  k_scan_a<<<nb, SCAN_B, 0, stream>>>(cnt, bsum, n);
  k_scan_b<<<1, 512, 0, stream>>>(bsum, nb, rowptr + n, E);
  k_scan_c<<<nb, SCAN_B, 0, stream>>>(cnt, bsum, rowptr, n);
  k_norm2<<<cdiv_i(n, 256), 256, 0, stream>>>(outnorm, cnt, innorm, invind, n);
  k_fill2<<<cdiv_i(E, 256), 256, 0, stream>>>(src, dst, rowptr, rank, csr, E);

  // ---- encoder MLP ----
  k_gemm_mfma<128,4,1,0,0,0><<<dim3(nt,1), 256, 0, stream>>>(features, encW1, encb1, nullptr, hbuf, n, 64);
  k_gemm_mfma<64, 2,1,0,0,0><<<dim3(nt,1), 256, 0, stream>>>(hbuf, encW2, encb2, nullptr, nbhw, n, 32);
  k_gemm_mfma<32, 4,0,0,0,0><<<dim3(nt,2), 256, 0, stream>>>(nbhw, encW3, encb3, nullptr, h128, n, 128);

  // ---- layer 0 ----
  k_gemm_mfma<128,4,0,0,1,1><<<dim3(nt,1), 256, 0, stream>>>(h128, W0, nullptr, outnorm, (float*)hw_bf, n, 64);
  k_gather_bf<<<cdiv_i(n, 4), 256, 0, stream>>>(hw_bf, rowptr, csr, agg, n);
  hipMemsetAsync(bnsum, 0, 128 * sizeof(float), stream);
  k_bnstats<<<512, 256, 0, stream>>>(agg, innorm, b0, bnsum, bnsq, n);
  k_bnfin<<<1, 64, 0, stream>>>(bnsum, bnsq, gamma, beta, bnscale, bnshift, 1.f / (float)n);
  k_post<<<cdiv_i(n * 64, 256), 256, 0, stream>>>(agg, innorm, b0, bnscale, bnshift, nullptr, hbuf, h_bf, n * 64);

  // ---- layers 1..3 ----
  for (int i = 1; i < 4; ++i){
    const float* Wi = Wrest + (size_t)(i - 1) * 64 * 64;
    const float* bi = brest + (size_t)(i - 1) * 64;
    // neighbor sum from bf16 shadow of h
    k_gather_bf<<<cdiv_i(n, 4), 256, 0, stream>>>(h_bf, rowptr, csr, nbhw, n);
    // attention gate
    k_gemm_mfma<64,4,0,0,0,0><<<dim3(nt,1), 256, 0, stream>>>(hbuf, attW1, attb1, nullptr, vbuf, n, 64);
    k_gemm_mfma<64,4,1,1,1,0><<<dim3(nt,1), 256, 0, stream>>>(nbhw, attW1 + 64 * 64, nullptr, invind, vbuf, n, 64);
    k_attupd<<<cdiv_i(n, 4), 256, 0, stream>>>(vbuf, attW2, attb2, nbhw, invind, hbuf, n);
    // conv: hw_bf = bf16((h*outnorm)@Wi); gather; stats; post (+res)
    k_gemm_mfma<64,4,0,0,1,1><<<dim3(nt,1), 256, 0, stream>>>(hbuf, Wi, nullptr, outnorm, (float*)hw_bf, n, 64);
    k_gather_bf<<<cdiv_i(n, 4), 256, 0, stream>>>(hw_bf, rowptr, csr, agg, n);
    hipMemsetAsync(bnsum, 0, 128 * sizeof(float), stream);
    k_bnstats<<<512, 256, 0, stream>>>(agg, innorm, bi, bnsum, bnsq, n);
    k_bnfin<<<1, 64, 0, stream>>>(bnsum, bnsq, gamma + i * 64, beta + i * 64, bnscale, bnshift, 1.f / (float)n);
    k_post<<<cdiv_i(n * 64, 256), 256, 0, stream>>>(agg, innorm, bi, bnscale, bnshift, hbuf, hbuf,
                                                    (i < 3) ? h_bf : nullptr, n * 64);
  }

  // ---- classifier ----
  k_gemm_mfma<64,1,0,0,0,0><<<dim3(nt,1), 256, 0, stream>>>(hbuf, fcW, fcb, nullptr, out, n, 16);
}

// Round 9
// 1142.576 us; speedup vs baseline: 1.2588x; 1.0934x over previous
//
#include <hip/hip_runtime.h>
#include <hip/hip_bf16.h>
#include <math.h>

// EnhancedResGCN forward. N=100000, E=1600000, IN=128, H=64, C=16, L=4.
// Round 9: fused attention kernel (2 GEMMs + gate + update in one, no vbuf),
// bnfin folded into k_post, single upfront BN-stats memset.

#define EPS_BN 1e-5f

static inline int cdiv_i(int a, int b){ return (a + b - 1) / b; }

typedef __attribute__((ext_vector_type(8))) short bf16x8;
typedef __attribute__((ext_vector_type(4))) float f32x4;

__device__ inline short f2bf(float f){
  unsigned int u = __builtin_bit_cast(unsigned int, f);
  u += 0x7FFFu + ((u >> 16) & 1u);          // round-to-nearest-even
  return (short)(u >> 16);
}
__device__ inline float bf2f(unsigned short u){
  unsigned int x = ((unsigned int)u) << 16;
  return __builtin_bit_cast(float, x);
}

// ---------------- degree count + per-edge rank (merged cursor) ----------------
__global__ void k_cnt2(const int* __restrict__ src, const int* __restrict__ dst,
                       float* __restrict__ outd, int* __restrict__ cnt,
                       int* __restrict__ rank, int E){
  int e = blockIdx.x * blockDim.x + threadIdx.x;
  if (e < E){
    atomicAdd(&outd[src[e]], 1.f);
    rank[e] = atomicAdd(&cnt[dst[e]], 1);
  }
}

__global__ void k_norm2(float* __restrict__ outn, const int* __restrict__ cnt,
                        float* __restrict__ innorm, float* __restrict__ invind, int n){
  int i = blockIdx.x * blockDim.x + threadIdx.x;
  if (i < n){
    float od = fmaxf(outn[i], 1.f);
    float id = fmaxf((float)cnt[i], 1.f);
    outn[i]   = rsqrtf(od);
    innorm[i] = rsqrtf(id);
    invind[i] = 1.f / id;
  }
}

// ---------------- exclusive scan of cnt[n] -> rowptr ----------------
#define SCAN_B 256
__global__ void k_scan_a(const int* __restrict__ cnt, int* __restrict__ bsum, int n){
  __shared__ int sm[SCAN_B];
  int i = blockIdx.x * SCAN_B + threadIdx.x;
  sm[threadIdx.x] = (i < n) ? cnt[i] : 0;
  __syncthreads();
  for (int s = SCAN_B / 2; s; s >>= 1){
    if (threadIdx.x < s) sm[threadIdx.x] += sm[threadIdx.x + s];
    __syncthreads();
  }
  if (threadIdx.x == 0) bsum[blockIdx.x] = sm[0];
}

__global__ void k_scan_b(int* __restrict__ bsum, int nb, int* __restrict__ rowptr_n, int E){
  __shared__ int sm[512];
  int t = threadIdx.x;
  int orig = (t < nb) ? bsum[t] : 0;
  sm[t] = orig;
  __syncthreads();
  for (int off = 1; off < 512; off <<= 1){
    int v = (t >= off) ? sm[t - off] : 0;
    __syncthreads();
    sm[t] += v;
    __syncthreads();
  }
  if (t < nb) bsum[t] = sm[t] - orig;
  if (t == 0) *rowptr_n = E;
}

__global__ void k_scan_c(const int* __restrict__ cnt, const int* __restrict__ bsum,
                         int* __restrict__ rowptr, int n){
  __shared__ int sm[SCAN_B];
  int i = blockIdx.x * SCAN_B + threadIdx.x;
  int orig = (i < n) ? cnt[i] : 0;
  sm[threadIdx.x] = orig;
  __syncthreads();
  for (int off = 1; off < SCAN_B; off <<= 1){
    int v = (threadIdx.x >= off) ? sm[threadIdx.x - off] : 0;
    __syncthreads();
    sm[threadIdx.x] += v;
    __syncthreads();
  }
  if (i < n) rowptr[i] = sm[threadIdx.x] - orig + bsum[blockIdx.x];
}

// atomic-free fill using precomputed rank
__global__ void k_fill2(const int* __restrict__ src, const int* __restrict__ dst,
                        const int* __restrict__ rowptr, const int* __restrict__ rank,
                        int* __restrict__ csr, int E){
  int e = blockIdx.x * blockDim.x + threadIdx.x;
  if (e < E){
    csr[rowptr[dst[e]] + rank[e]] = src[e];
  }
}

// ---------------- MFMA GEMM: Y = (RS? X*rscale : X) @ W (+bias)(+=Y)(relu), OBF: bf16 out ----
template<int K, int NF, int RELU, int ACC, int RS, int OBF>
__global__ __launch_bounds__(256) void k_gemm_mfma(
    const float* __restrict__ X, const float* __restrict__ W,
    const float* __restrict__ bias, const float* __restrict__ rscale,
    float* __restrict__ Y, int n, int nout)
{
  constexpr int KSTEPS = K / 32;
  __shared__ short WP[KSTEPS * NF * 4 * 16 * 8];   // fragment-ordered bf16 W

  const int tid  = threadIdx.x;
  const int wave = tid >> 6, lane = tid & 63;
  const int lrow = lane & 15, lgrp = lane >> 4;
  const int col0 = blockIdx.y * (NF * 16);

  for (int i = tid; i < KSTEPS * NF * 4 * 16; i += 256){
    int c  = i & 15;
    int kg = (i >> 4) & 3;
    int t2 = i >> 6;
    int nf = t2 % NF, kstep = t2 / NF;
    int col = col0 + nf * 16 + c;
    short* dst8 = &WP[((kstep * NF + nf) * 4 + kg) * 128 + c * 8];
#pragma unroll
    for (int j = 0; j < 8; ++j){
      int k = kstep * 32 + kg * 8 + j;
      dst8[j] = (col < nout) ? f2bf(W[(size_t)k * nout + col]) : (short)0;
    }
  }
  __syncthreads();

  const int row = blockIdx.x * 64 + wave * 16 + lrow;
  const bool rok = (row < n);
  const float rs = (RS && rok) ? rscale[row] : 1.f;

  f32x4 acc[NF];
#pragma unroll
  for (int nf = 0; nf < NF; ++nf) acc[nf] = (f32x4){0.f, 0.f, 0.f, 0.f};

#pragma unroll
  for (int kstep = 0; kstep < KSTEPS; ++kstep){
    bf16x8 a;
    if (rok){
      const float* p = X + (size_t)row * K + kstep * 32 + lgrp * 8;
      float4 v0 = *reinterpret_cast<const float4*>(p);
      float4 v1 = *reinterpret_cast<const float4*>(p + 4);
      a[0] = f2bf(v0.x * rs); a[1] = f2bf(v0.y * rs);
      a[2] = f2bf(v0.z * rs); a[3] = f2bf(v0.w * rs);
      a[4] = f2bf(v1.x * rs); a[5] = f2bf(v1.y * rs);
      a[6] = f2bf(v1.z * rs); a[7] = f2bf(v1.w * rs);
    } else {
#pragma unroll
      for (int j = 0; j < 8; ++j) a[j] = 0;
    }
#pragma unroll
    for (int nf = 0; nf < NF; ++nf){
      bf16x8 b = *reinterpret_cast<const bf16x8*>(
          &WP[((kstep * NF + nf) * 4 + lgrp) * 128 + lrow * 8]);
      acc[nf] = __builtin_amdgcn_mfma_f32_16x16x32_bf16(a, b, acc[nf], 0, 0, 0);
    }
  }

#pragma unroll
  for (int nf = 0; nf < NF; ++nf){
    int col = col0 + nf * 16 + lrow;
    if (col >= nout) continue;
    float bv = bias ? bias[col] : 0.f;
#pragma unroll
    for (int r = 0; r < 4; ++r){
      int orow = blockIdx.x * 64 + wave * 16 + lgrp * 4 + r;
      if (orow >= n) continue;
      float v = acc[nf][r] + bv;
      size_t o = (size_t)orow * nout + col;
      if (ACC) v += Y[o];
      if (RELU) v = fmaxf(v, 0.f);
      if (OBF) ((short*)Y)[o] = f2bf(v);
      else     Y[o] = v;
    }
  }
}

// ---------------- fused attention: v=relu([h|nb*invind]@W1+b1); a=sigmoid(v.W2+b2); h+=a*nbm ----
// 256 thr = 4 waves x 16 rows; NF=4 -> full 64-col v row per wave, never stored.
__global__ __launch_bounds__(256) void k_att(
    float* __restrict__ h, const float* __restrict__ nb,
    const float* __restrict__ invind, const float* __restrict__ W1,
    const float* __restrict__ b1, const float* __restrict__ W2,
    const float* __restrict__ b2, int n)
{
  constexpr int NF = 4, KSTEPS = 4;                  // K = 128 (64 h + 64 nbm)
  __shared__ short WP[KSTEPS * NF * 4 * 16 * 8];     // 16 KB

  const int tid  = threadIdx.x;
  const int wave = tid >> 6, lane = tid & 63;
  const int lrow = lane & 15, lgrp = lane >> 4;

  for (int i = tid; i < KSTEPS * NF * 4 * 16; i += 256){
    int c  = i & 15;
    int kg = (i >> 4) & 3;
    int t2 = i >> 6;
    int nf = t2 % NF, kstep = t2 / NF;
    short* dst8 = &WP[((kstep * NF + nf) * 4 + kg) * 128 + c * 8];
#pragma unroll
    for (int j = 0; j < 8; ++j){
      int k = kstep * 32 + kg * 8 + j;               // 0..127 row of W1
      dst8[j] = f2bf(W1[(size_t)k * 64 + nf * 16 + c]);
    }
  }
  __syncthreads();

  const int row = blockIdx.x * 64 + wave * 16 + lrow;
  const bool rok = (row < n);
  const float iv = rok ? invind[row] : 0.f;

  f32x4 acc[NF];
#pragma unroll
  for (int nf = 0; nf < NF; ++nf) acc[nf] = (f32x4){0.f, 0.f, 0.f, 0.f};

#pragma unroll
  for (int kstep = 0; kstep < KSTEPS; ++kstep){
    bf16x8 a;
    if (rok){
      const float* base = (kstep < 2) ? h : nb;
      const float sc = (kstep < 2) ? 1.f : iv;
      const float* p = base + (size_t)row * 64 + (kstep & 1) * 32 + lgrp * 8;
      float4 v0 = *reinterpret_cast<const float4*>(p);
      float4 v1 = *reinterpret_cast<const float4*>(p + 4);
      a[0] = f2bf(v0.x * sc); a[1] = f2bf(v0.y * sc);
      a[2] = f2bf(v0.z * sc); a[3] = f2bf(v0.w * sc);
      a[4] = f2bf(v1.x * sc); a[5] = f2bf(v1.y * sc);
      a[6] = f2bf(v1.z * sc); a[7] = f2bf(v1.w * sc);
    } else {
#pragma unroll
      for (int j = 0; j < 8; ++j) a[j] = 0;
    }
#pragma unroll
    for (int nf = 0; nf < NF; ++nf){
      bf16x8 b = *reinterpret_cast<const bf16x8*>(
          &WP[((kstep * NF + nf) * 4 + lgrp) * 128 + lrow * 8]);
      acc[nf] = __builtin_amdgcn_mfma_f32_16x16x32_bf16(a, b, acc[nf], 0, 0, 0);
    }
  }

  // gate + update per output row r: rows wave*16 + lgrp*4 + r
  const float w2l[4] = {W2[lrow], W2[16 + lrow], W2[32 + lrow], W2[48 + lrow]};
  const float b2v = b2[0];
#pragma unroll
  for (int r = 0; r < 4; ++r){
    int orow = blockIdx.x * 64 + wave * 16 + lgrp * 4 + r;
    // partial dot over this lane's 4 columns (v = relu(acc + b1))
    float p = 0.f;
#pragma unroll
    for (int nf = 0; nf < NF; ++nf)
      p += fmaxf(acc[nf][r] + b1[nf * 16 + lrow], 0.f) * w2l[nf];
    // reduce across the 16 lanes of this column-group (lane bits 0..3)
    p += __shfl_xor(p, 1); p += __shfl_xor(p, 2);
    p += __shfl_xor(p, 4); p += __shfl_xor(p, 8);
    if (orow < n){
      float a = 1.f / (1.f + expf(-(p + b2v)));
      float ivr = invind[orow];
      float4 nbv = *reinterpret_cast<const float4*>(&nb[(size_t)orow * 64 + lrow * 4]);
      float4 hv  = *reinterpret_cast<float4*>(&h[(size_t)orow * 64 + lrow * 4]);
      hv.x += a * nbv.x * ivr; hv.y += a * nbv.y * ivr;
      hv.z += a * nbv.z * ivr; hv.w += a * nbv.w * ivr;
      *reinterpret_cast<float4*>(&h[(size_t)orow * 64 + lrow * 4]) = hv;
    }
  }
}

// ---------------- CSR gather (bf16 rows in, fp32 out): out[d] = sum x[src] ----------------
__global__ void k_gather_bf(const unsigned short* __restrict__ x,
                            const int* __restrict__ rowptr, const int* __restrict__ csr,
                            float* __restrict__ out, int n){
  int node = blockIdx.x * 4 + (threadIdx.x >> 6);
  int f = threadIdx.x & 63;
  if (node >= n) return;
  int beg = rowptr[node], end = rowptr[node + 1];
  float a0 = 0.f, a1 = 0.f;
  int e = beg;
  for (; e + 1 < end; e += 2){
    int s0 = csr[e], s1 = csr[e + 1];
    a0 += bf2f(x[(size_t)s0 * 64 + f]);
    a1 += bf2f(x[(size_t)s1 * 64 + f]);
  }
  if (e < end) a0 += bf2f(x[(size_t)csr[e] * 64 + f]);
  out[(size_t)node * 64 + f] = a0 + a1;
}

// ---------------- BatchNorm stats over z = agg*in_norm + b ----------------
__global__ void k_bnstats(const float* __restrict__ agg, const float* __restrict__ innorm,
                          const float* __restrict__ b, float* __restrict__ sum,
                          float* __restrict__ sumsq, int n){
  __shared__ float s1[4][64], s2[4][64];
  int f = threadIdx.x & 63, g = threadIdx.x >> 6;
  float bf = b[f];
  float a1 = 0.f, a2 = 0.f;
  for (int row = blockIdx.x * 4 + g; row < n; row += gridDim.x * 4){
    float z = agg[(size_t)row * 64 + f] * innorm[row] + bf;
    a1 += z; a2 += z * z;
  }
  s1[g][f] = a1; s2[g][f] = a2;
  __syncthreads();
  if (threadIdx.x < 64){
    atomicAdd(&sum[f],   s1[0][f] + s1[1][f] + s1[2][f] + s1[3][f]);
    atomicAdd(&sumsq[f], s2[0][f] + s2[1][f] + s2[2][f] + s2[3][f]);
  }
}

// ---------------- epilogue (bnfin fused): h = relu(BN(agg*innorm+b) [+hres]); bf16 shadow ----
__global__ void k_post(const float* __restrict__ agg, const float* __restrict__ innorm,
                       const float* __restrict__ b, const float* __restrict__ bnsum,
                       const float* __restrict__ bnsq, const float* __restrict__ gamma,
                       const float* __restrict__ beta, float inv_n,
                       const float* __restrict__ hres,
                       float* __restrict__ hout, unsigned short* __restrict__ hbf, int n64){
  int i = blockIdx.x * blockDim.x + threadIdx.x;
  if (i >= n64) return;
  int f = i & 63, row = i >> 6;
  float mu  = bnsum[f] * inv_n;
  float var = bnsq[f] * inv_n - mu * mu;
  float sc  = gamma[f] * rsqrtf(var + EPS_BN);
  float sh  = beta[f] - mu * sc;
  float z = agg[i] * innorm[row] + b[f];
  z = z * sc + sh;
  if (hres) z += hres[i];
  float r = fmaxf(z, 0.f);
  hout[i] = r;
  if (hbf) hbf[i] = (unsigned short)f2bf(r);
}

extern "C" void kernel_launch(void* const* d_in, const int* in_sizes, int n_in,
                              void* d_out, int out_size, void* d_ws, size_t ws_size,
                              hipStream_t stream) {
  const float* features = (const float*)d_in[0];
  const int*   src      = (const int*)d_in[1];
  const int*   dst      = (const int*)d_in[2];
  const float* encW1 = (const float*)d_in[3];  const float* encb1 = (const float*)d_in[4];
  const float* encW2 = (const float*)d_in[5];  const float* encb2 = (const float*)d_in[6];
  const float* encW3 = (const float*)d_in[7];  const float* encb3 = (const float*)d_in[8];
  const float* attW1 = (const float*)d_in[9];  const float* attb1 = (const float*)d_in[10];
  const float* attW2 = (const float*)d_in[11]; const float* attb2 = (const float*)d_in[12];
  const float* W0    = (const float*)d_in[13]; const float* b0    = (const float*)d_in[14];
  const float* Wrest = (const float*)d_in[15]; const float* brest = (const float*)d_in[16];
  const float* gamma = (const float*)d_in[17]; const float* beta  = (const float*)d_in[18];
  const float* fcW   = (const float*)d_in[19]; const float* fcb   = (const float*)d_in[20];
  float* out = (float*)d_out;

  const int n = in_sizes[0] / 128;   // 100000
  const int E = in_sizes[1];         // 1600000

  // float workspace
  float* ws      = (float*)d_ws;
  float* h128    = ws;                          // N*128 f32 (enc out; dead after L0 GEMM)
  float* agg     = h128;                        // alias: first N*64 of h128
  unsigned short* h_bf = (unsigned short*)(h128 + (size_t)n * 64);  // second half of h128
  float* hbuf    = h128 + (size_t)n * 128;      // N*64 f32 (h)
  float* nbhw    = hbuf + (size_t)n * 64;       // N*64 f32 scratch (t2 / rank / nb / hw_bf)
  float* outnorm = nbhw + (size_t)n * 64;
  float* innorm  = outnorm + n;
  float* invind  = innorm + n;
  float* bnsum   = invind + n;                  // 4 layers x 64
  float* bnsq    = bnsum + 256;                 // 4 layers x 64
  // int workspace (CSR)
  int* cnt    = (int*)(bnsq + 256);
  int* rowptr = cnt + n;                        // n+1
  int* csr    = rowptr + n + 1;                 // E
  int* bsum   = csr + E;                        // 512
  // aliases with sequential lifetimes
  int*   rank  = (int*)nbhw;                    // E ints, dead before encoder uses nbhw
  unsigned short* hw_bf = (unsigned short*)nbhw;// conv GEMM bf16 out (GEMM->gather only)

  const int nt = cdiv_i(n, 64);
  const int nb = cdiv_i(n, SCAN_B);
  const float inv_n = 1.f / (float)n;

  // ---- degrees, norms, CSR build ----
  hipMemsetAsync(outnorm, 0, (size_t)n * sizeof(float), stream);
  hipMemsetAsync(cnt, 0, (size_t)n * sizeof(int), stream);
  hipMemsetAsync(bnsum, 0, 512 * sizeof(float), stream);
  k_cnt2<<<cdiv_i(E, 256), 256, 0, stream>>>(src, dst, outnorm, cnt, rank, E);
  k_scan_a<<<nb, SCAN_B, 0, stream>>>(cnt, bsum, n);
  k_scan_b<<<1, 512, 0, stream>>>(bsum, nb, rowptr + n, E);
  k_scan_c<<<nb, SCAN_B, 0, stream>>>(cnt, bsum, rowptr, n);
  k_norm2<<<cdiv_i(n, 256), 256, 0, stream>>>(outnorm, cnt, innorm, invind, n);
  k_fill2<<<cdiv_i(E, 256), 256, 0, stream>>>(src, dst, rowptr, rank, csr, E);

  // ---- encoder MLP ----
  k_gemm_mfma<128,4,1,0,0,0><<<dim3(nt,1), 256, 0, stream>>>(features, encW1, encb1, nullptr, hbuf, n, 64);
  k_gemm_mfma<64, 2,1,0,0,0><<<dim3(nt,1), 256, 0, stream>>>(hbuf, encW2, encb2, nullptr, nbhw, n, 32);
  k_gemm_mfma<32, 4,0,0,0,0><<<dim3(nt,2), 256, 0, stream>>>(nbhw, encW3, encb3, nullptr, h128, n, 128);

  // ---- layer 0 ----
  k_gemm_mfma<128,4,0,0,1,1><<<dim3(nt,1), 256, 0, stream>>>(h128, W0, nullptr, outnorm, (float*)hw_bf, n, 64);
  k_gather_bf<<<cdiv_i(n, 4), 256, 0, stream>>>(hw_bf, rowptr, csr, agg, n);
  k_bnstats<<<512, 256, 0, stream>>>(agg, innorm, b0, bnsum, bnsq, n);
  k_post<<<cdiv_i(n * 64, 256), 256, 0, stream>>>(agg, innorm, b0, bnsum, bnsq, gamma, beta, inv_n,
                                                  nullptr, hbuf, h_bf, n * 64);

  // ---- layers 1..3 ----
  for (int i = 1; i < 4; ++i){
    const float* Wi = Wrest + (size_t)(i - 1) * 64 * 64;
    const float* bi = brest + (size_t)(i - 1) * 64;
    // neighbor sum from bf16 shadow of h
    k_gather_bf<<<cdiv_i(n, 4), 256, 0, stream>>>(h_bf, rowptr, csr, nbhw, n);
    // fused attention gate + update
    k_att<<<nt, 256, 0, stream>>>(hbuf, nbhw, invind, attW1, attb1, attW2, attb2, n);
    // conv: hw_bf = bf16((h*outnorm)@Wi); gather; stats; post (+res)
    k_gemm_mfma<64,4,0,0,1,1><<<dim3(nt,1), 256, 0, stream>>>(hbuf, Wi, nullptr, outnorm, (float*)hw_bf, n, 64);
    k_gather_bf<<<cdiv_i(n, 4), 256, 0, stream>>>(hw_bf, rowptr, csr, agg, n);
    k_bnstats<<<512, 256, 0, stream>>>(agg, innorm, bi, bnsum + i * 64, bnsq + i * 64, n);
    k_post<<<cdiv_i(n * 64, 256), 256, 0, stream>>>(agg, innorm, bi, bnsum + i * 64, bnsq + i * 64,
                                                    gamma + i * 64, beta + i * 64, inv_n,
                                                    hbuf, hbuf, (i < 3) ? h_bf : nullptr, n * 64);
  }

  // ---- classifier ----
  k_gemm_mfma<64,1,0,0,0,0><<<dim3(nt,1), 256, 0, stream>>>(hbuf, fcW, fcb, nullptr, out, n, 16);
}

// Round 10
// 1133.446 us; speedup vs baseline: 1.2689x; 1.0081x over previous
//
#include <hip/hip_runtime.h>
#include <hip/hip_bf16.h>
#include <math.h>

// EnhancedResGCN forward. N=100000, E=1600000, IN=128, H=64, C=16, L=4.
// Round 10: (1) ILP x4 in k_cnt2/k_fill2 (atomic latency-vs-throughput experiment),
// (2) enc3 output bf16 + bf16-input GEMM path for the layer-0 conv.

#define EPS_BN 1e-5f

static inline int cdiv_i(int a, int b){ return (a + b - 1) / b; }

typedef __attribute__((ext_vector_type(8))) short bf16x8;
typedef __attribute__((ext_vector_type(4))) float f32x4;

__device__ inline short f2bf(float f){
  unsigned int u = __builtin_bit_cast(unsigned int, f);
  u += 0x7FFFu + ((u >> 16) & 1u);          // round-to-nearest-even
  return (short)(u >> 16);
}
__device__ inline float bf2f(unsigned short u){
  unsigned int x = ((unsigned int)u) << 16;
  return __builtin_bit_cast(float, x);
}

// ---------------- degree count + per-edge rank, 4 edges/thread (ILP) ----------------
__global__ void k_cnt2(const int* __restrict__ src, const int* __restrict__ dst,
                       float* __restrict__ outd, int* __restrict__ cnt,
                       int* __restrict__ rank, int E){
  int base = blockIdx.x * (blockDim.x * 4) + threadIdx.x;
#pragma unroll
  for (int j = 0; j < 4; ++j){
    int e = base + j * 256;
    if (e < E){
      atomicAdd(&outd[src[e]], 1.f);
      rank[e] = atomicAdd(&cnt[dst[e]], 1);
    }
  }
}

__global__ void k_norm2(float* __restrict__ outn, const int* __restrict__ cnt,
                        float* __restrict__ innorm, float* __restrict__ invind, int n){
  int i = blockIdx.x * blockDim.x + threadIdx.x;
  if (i < n){
    float od = fmaxf(outn[i], 1.f);
    float id = fmaxf((float)cnt[i], 1.f);
    outn[i]   = rsqrtf(od);
    innorm[i] = rsqrtf(id);
    invind[i] = 1.f / id;
  }
}

// ---------------- exclusive scan of cnt[n] -> rowptr ----------------
#define SCAN_B 256
__global__ void k_scan_a(const int* __restrict__ cnt, int* __restrict__ bsum, int n){
  __shared__ int sm[SCAN_B];
  int i = blockIdx.x * SCAN_B + threadIdx.x;
  sm[threadIdx.x] = (i < n) ? cnt[i] : 0;
  __syncthreads();
  for (int s = SCAN_B / 2; s; s >>= 1){
    if (threadIdx.x < s) sm[threadIdx.x] += sm[threadIdx.x + s];
    __syncthreads();
  }
  if (threadIdx.x == 0) bsum[blockIdx.x] = sm[0];
}

__global__ void k_scan_b(int* __restrict__ bsum, int nb, int* __restrict__ rowptr_n, int E){
  __shared__ int sm[512];
  int t = threadIdx.x;
  int orig = (t < nb) ? bsum[t] : 0;
  sm[t] = orig;
  __syncthreads();
  for (int off = 1; off < 512; off <<= 1){
    int v = (t >= off) ? sm[t - off] : 0;
    __syncthreads();
    sm[t] += v;
    __syncthreads();
  }
  if (t < nb) bsum[t] = sm[t] - orig;
  if (t == 0) *rowptr_n = E;
}

__global__ void k_scan_c(const int* __restrict__ cnt, const int* __restrict__ bsum,
                         int* __restrict__ rowptr, int n){
  __shared__ int sm[SCAN_B];
  int i = blockIdx.x * SCAN_B + threadIdx.x;
  int orig = (i < n) ? cnt[i] : 0;
  sm[threadIdx.x] = orig;
  __syncthreads();
  for (int off = 1; off < SCAN_B; off <<= 1){
    int v = (threadIdx.x >= off) ? sm[threadIdx.x - off] : 0;
    __syncthreads();
    sm[threadIdx.x] += v;
    __syncthreads();
  }
  if (i < n) rowptr[i] = sm[threadIdx.x] - orig + bsum[blockIdx.x];
}

// atomic-free fill using precomputed rank, 4 edges/thread
__global__ void k_fill2(const int* __restrict__ src, const int* __restrict__ dst,
                        const int* __restrict__ rowptr, const int* __restrict__ rank,
                        int* __restrict__ csr, int E){
  int base = blockIdx.x * (blockDim.x * 4) + threadIdx.x;
#pragma unroll
  for (int j = 0; j < 4; ++j){
    int e = base + j * 256;
    if (e < E) csr[rowptr[dst[e]] + rank[e]] = src[e];
  }
}

// ---------------- MFMA GEMM: Y = (RS? X*rscale : X) @ W (+bias)(+=Y)(relu) ----
// IT: 0 = fp32 X, 1 = bf16 X.  OBF: bf16 output.
template<int K, int NF, int RELU, int ACC, int RS, int OBF, int IT>
__global__ __launch_bounds__(256) void k_gemm_mfma(
    const float* __restrict__ X, const float* __restrict__ W,
    const float* __restrict__ bias, const float* __restrict__ rscale,
    float* __restrict__ Y, int n, int nout)
{
  constexpr int KSTEPS = K / 32;
  __shared__ short WP[KSTEPS * NF * 4 * 16 * 8];   // fragment-ordered bf16 W

  const int tid  = threadIdx.x;
  const int wave = tid >> 6, lane = tid & 63;
  const int lrow = lane & 15, lgrp = lane >> 4;
  const int col0 = blockIdx.y * (NF * 16);

  for (int i = tid; i < KSTEPS * NF * 4 * 16; i += 256){
    int c  = i & 15;
    int kg = (i >> 4) & 3;
    int t2 = i >> 6;
    int nf = t2 % NF, kstep = t2 / NF;
    int col = col0 + nf * 16 + c;
    short* dst8 = &WP[((kstep * NF + nf) * 4 + kg) * 128 + c * 8];
#pragma unroll
    for (int j = 0; j < 8; ++j){
      int k = kstep * 32 + kg * 8 + j;
      dst8[j] = (col < nout) ? f2bf(W[(size_t)k * nout + col]) : (short)0;
    }
  }
  __syncthreads();

  const int row = blockIdx.x * 64 + wave * 16 + lrow;
  const bool rok = (row < n);
  const float rs = (RS && rok) ? rscale[row] : 1.f;

  f32x4 acc[NF];
#pragma unroll
  for (int nf = 0; nf < NF; ++nf) acc[nf] = (f32x4){0.f, 0.f, 0.f, 0.f};

#pragma unroll
  for (int kstep = 0; kstep < KSTEPS; ++kstep){
    bf16x8 a;
    if (rok){
      if (IT){
        const unsigned short* p = (const unsigned short*)X + (size_t)row * K + kstep * 32 + lgrp * 8;
        bf16x8 raw = *reinterpret_cast<const bf16x8*>(p);
        if (RS){
#pragma unroll
          for (int j = 0; j < 8; ++j) a[j] = f2bf(bf2f((unsigned short)raw[j]) * rs);
        } else a = raw;
      } else {
        const float* p = X + (size_t)row * K + kstep * 32 + lgrp * 8;
        float4 v0 = *reinterpret_cast<const float4*>(p);
        float4 v1 = *reinterpret_cast<const float4*>(p + 4);
        a[0] = f2bf(v0.x * rs); a[1] = f2bf(v0.y * rs);
        a[2] = f2bf(v0.z * rs); a[3] = f2bf(v0.w * rs);
        a[4] = f2bf(v1.x * rs); a[5] = f2bf(v1.y * rs);
        a[6] = f2bf(v1.z * rs); a[7] = f2bf(v1.w * rs);
      }
    } else {
#pragma unroll
      for (int j = 0; j < 8; ++j) a[j] = 0;
    }
#pragma unroll
    for (int nf = 0; nf < NF; ++nf){
      bf16x8 b = *reinterpret_cast<const bf16x8*>(
          &WP[((kstep * NF + nf) * 4 + lgrp) * 128 + lrow * 8]);
      acc[nf] = __builtin_amdgcn_mfma_f32_16x16x32_bf16(a, b, acc[nf], 0, 0, 0);
    }
  }

#pragma unroll
  for (int nf = 0; nf < NF; ++nf){
    int col = col0 + nf * 16 + lrow;
    if (col >= nout) continue;
    float bv = bias ? bias[col] : 0.f;
#pragma unroll
    for (int r = 0; r < 4; ++r){
      int orow = blockIdx.x * 64 + wave * 16 + lgrp * 4 + r;
      if (orow >= n) continue;
      float v = acc[nf][r] + bv;
      size_t o = (size_t)orow * nout + col;
      if (ACC) v += Y[o];
      if (RELU) v = fmaxf(v, 0.f);
      if (OBF) ((short*)Y)[o] = f2bf(v);
      else     Y[o] = v;
    }
  }
}

// ---------------- fused attention: v=relu([h|nb*invind]@W1+b1); a=sigmoid(v.W2+b2); h+=a*nbm ----
__global__ __launch_bounds__(256) void k_att(
    float* __restrict__ h, const float* __restrict__ nb,
    const float* __restrict__ invind, const float* __restrict__ W1,
    const float* __restrict__ b1, const float* __restrict__ W2,
    const float* __restrict__ b2, int n)
{
  constexpr int NF = 4, KSTEPS = 4;                  // K = 128 (64 h + 64 nbm)
  __shared__ short WP[KSTEPS * NF * 4 * 16 * 8];     // 16 KB

  const int tid  = threadIdx.x;
  const int wave = tid >> 6, lane = tid & 63;
  const int lrow = lane & 15, lgrp = lane >> 4;

  for (int i = tid; i < KSTEPS * NF * 4 * 16; i += 256){
    int c  = i & 15;
    int kg = (i >> 4) & 3;
    int t2 = i >> 6;
    int nf = t2 % NF, kstep = t2 / NF;
    short* dst8 = &WP[((kstep * NF + nf) * 4 + kg) * 128 + c * 8];
#pragma unroll
    for (int j = 0; j < 8; ++j){
      int k = kstep * 32 + kg * 8 + j;               // 0..127 row of W1
      dst8[j] = f2bf(W1[(size_t)k * 64 + nf * 16 + c]);
    }
  }
  __syncthreads();

  const int row = blockIdx.x * 64 + wave * 16 + lrow;
  const bool rok = (row < n);
  const float iv = rok ? invind[row] : 0.f;

  f32x4 acc[NF];
#pragma unroll
  for (int nf = 0; nf < NF; ++nf) acc[nf] = (f32x4){0.f, 0.f, 0.f, 0.f};

#pragma unroll
  for (int kstep = 0; kstep < KSTEPS; ++kstep){
    bf16x8 a;
    if (rok){
      const float* base = (kstep < 2) ? h : nb;
      const float sc = (kstep < 2) ? 1.f : iv;
      const float* p = base + (size_t)row * 64 + (kstep & 1) * 32 + lgrp * 8;
      float4 v0 = *reinterpret_cast<const float4*>(p);
      float4 v1 = *reinterpret_cast<const float4*>(p + 4);
      a[0] = f2bf(v0.x * sc); a[1] = f2bf(v0.y * sc);
      a[2] = f2bf(v0.z * sc); a[3] = f2bf(v0.w * sc);
      a[4] = f2bf(v1.x * sc); a[5] = f2bf(v1.y * sc);
      a[6] = f2bf(v1.z * sc); a[7] = f2bf(v1.w * sc);
    } else {
#pragma unroll
      for (int j = 0; j < 8; ++j) a[j] = 0;
    }
#pragma unroll
    for (int nf = 0; nf < NF; ++nf){
      bf16x8 b = *reinterpret_cast<const bf16x8*>(
          &WP[((kstep * NF + nf) * 4 + lgrp) * 128 + lrow * 8]);
      acc[nf] = __builtin_amdgcn_mfma_f32_16x16x32_bf16(a, b, acc[nf], 0, 0, 0);
    }
  }

  const float w2l[4] = {W2[lrow], W2[16 + lrow], W2[32 + lrow], W2[48 + lrow]};
  const float b2v = b2[0];
#pragma unroll
  for (int r = 0; r < 4; ++r){
    int orow = blockIdx.x * 64 + wave * 16 + lgrp * 4 + r;
    float p = 0.f;
#pragma unroll
    for (int nf = 0; nf < NF; ++nf)
      p += fmaxf(acc[nf][r] + b1[nf * 16 + lrow], 0.f) * w2l[nf];
    p += __shfl_xor(p, 1); p += __shfl_xor(p, 2);
    p += __shfl_xor(p, 4); p += __shfl_xor(p, 8);
    if (orow < n){
      float a = 1.f / (1.f + expf(-(p + b2v)));
      float ivr = invind[orow];
      float4 nbv = *reinterpret_cast<const float4*>(&nb[(size_t)orow * 64 + lrow * 4]);
      float4 hv  = *reinterpret_cast<float4*>(&h[(size_t)orow * 64 + lrow * 4]);
      hv.x += a * nbv.x * ivr; hv.y += a * nbv.y * ivr;
      hv.z += a * nbv.z * ivr; hv.w += a * nbv.w * ivr;
      *reinterpret_cast<float4*>(&h[(size_t)orow * 64 + lrow * 4]) = hv;
    }
  }
}

// ---------------- CSR gather (bf16 rows in, fp32 out): out[d] = sum x[src] ----------------
__global__ void k_gather_bf(const unsigned short* __restrict__ x,
                            const int* __restrict__ rowptr, const int* __restrict__ csr,
                            float* __restrict__ out, int n){
  int node = blockIdx.x * 4 + (threadIdx.x >> 6);
  int f = threadIdx.x & 63;
  if (node >= n) return;
  int beg = rowptr[node], end = rowptr[node + 1];
  float a0 = 0.f, a1 = 0.f;
  int e = beg;
  for (; e + 1 < end; e += 2){
    int s0 = csr[e], s1 = csr[e + 1];
    a0 += bf2f(x[(size_t)s0 * 64 + f]);
    a1 += bf2f(x[(size_t)s1 * 64 + f]);
  }
  if (e < end) a0 += bf2f(x[(size_t)csr[e] * 64 + f]);
  out[(size_t)node * 64 + f] = a0 + a1;
}

// ---------------- BatchNorm stats over z = agg*in_norm + b ----------------
__global__ void k_bnstats(const float* __restrict__ agg, const float* __restrict__ innorm,
                          const float* __restrict__ b, float* __restrict__ sum,
                          float* __restrict__ sumsq, int n){
  __shared__ float s1[4][64], s2[4][64];
  int f = threadIdx.x & 63, g = threadIdx.x >> 6;
  float bf = b[f];
  float a1 = 0.f, a2 = 0.f;
  for (int row = blockIdx.x * 4 + g; row < n; row += gridDim.x * 4){
    float z = agg[(size_t)row * 64 + f] * innorm[row] + bf;
    a1 += z; a2 += z * z;
  }
  s1[g][f] = a1; s2[g][f] = a2;
  __syncthreads();
  if (threadIdx.x < 64){
    atomicAdd(&sum[f],   s1[0][f] + s1[1][f] + s1[2][f] + s1[3][f]);
    atomicAdd(&sumsq[f], s2[0][f] + s2[1][f] + s2[2][f] + s2[3][f]);
  }
}

// ---------------- epilogue (bnfin fused): h = relu(BN(agg*innorm+b) [+hres]); bf16 shadow ----
__global__ void k_post(const float* __restrict__ agg, const float* __restrict__ innorm,
                       const float* __restrict__ b, const float* __restrict__ bnsum,
                       const float* __restrict__ bnsq, const float* __restrict__ gamma,
                       const float* __restrict__ beta, float inv_n,
                       const float* __restrict__ hres,
                       float* __restrict__ hout, unsigned short* __restrict__ hbf, int n64){
  int i = blockIdx.x * blockDim.x + threadIdx.x;
  if (i >= n64) return;
  int f = i & 63, row = i >> 6;
  float mu  = bnsum[f] * inv_n;
  float var = bnsq[f] * inv_n - mu * mu;
  float sc  = gamma[f] * rsqrtf(var + EPS_BN);
  float sh  = beta[f] - mu * sc;
  float z = agg[i] * innorm[row] + b[f];
  z = z * sc + sh;
  if (hres) z += hres[i];
  float r = fmaxf(z, 0.f);
  hout[i] = r;
  if (hbf) hbf[i] = (unsigned short)f2bf(r);
}

extern "C" void kernel_launch(void* const* d_in, const int* in_sizes, int n_in,
                              void* d_out, int out_size, void* d_ws, size_t ws_size,
                              hipStream_t stream) {
  const float* features = (const float*)d_in[0];
  const int*   src      = (const int*)d_in[1];
  const int*   dst      = (const int*)d_in[2];
  const float* encW1 = (const float*)d_in[3];  const float* encb1 = (const float*)d_in[4];
  const float* encW2 = (const float*)d_in[5];  const float* encb2 = (const float*)d_in[6];
  const float* encW3 = (const float*)d_in[7];  const float* encb3 = (const float*)d_in[8];
  const float* attW1 = (const float*)d_in[9];  const float* attb1 = (const float*)d_in[10];
  const float* attW2 = (const float*)d_in[11]; const float* attb2 = (const float*)d_in[12];
  const float* W0    = (const float*)d_in[13]; const float* b0    = (const float*)d_in[14];
  const float* Wrest = (const float*)d_in[15]; const float* brest = (const float*)d_in[16];
  const float* gamma = (const float*)d_in[17]; const float* beta  = (const float*)d_in[18];
  const float* fcW   = (const float*)d_in[19]; const float* fcb   = (const float*)d_in[20];
  float* out = (float*)d_out;

  const int n = in_sizes[0] / 128;   // 100000
  const int E = in_sizes[1];         // 1600000

  // float workspace
  float* ws      = (float*)d_ws;
  float* h128    = ws;                          // N*128 f32 region, sub-allocated:
  float* agg     = h128;                        //   [0, n*64)   f32 agg
  unsigned short* h_bf = (unsigned short*)(h128 + (size_t)n * 64);   // [n*64, n*96) as bf16 shadow
  unsigned short* enc_bf = (unsigned short*)(h128 + (size_t)n * 96); // [n*96, n*128) enc3 bf16 out
  float* hbuf    = h128 + (size_t)n * 128;      // N*64 f32 (h)
  float* nbhw    = hbuf + (size_t)n * 64;       // N*64 f32 scratch (t1/t2 / rank / nb / hw_bf)
  float* outnorm = nbhw + (size_t)n * 64;
  float* innorm  = outnorm + n;
  float* invind  = innorm + n;
  float* bnsum   = invind + n;                  // 4 layers x 64
  float* bnsq    = bnsum + 256;                 // 4 layers x 64
  // int workspace (CSR)
  int* cnt    = (int*)(bnsq + 256);
  int* rowptr = cnt + n;                        // n+1
  int* csr    = rowptr + n + 1;                 // E
  int* bsum   = csr + E;                        // 512
  // aliases with sequential lifetimes
  int*   rank  = (int*)nbhw;                    // E ints, dead before encoder uses nbhw
  unsigned short* hw_bf = (unsigned short*)nbhw;// conv GEMM bf16 out (GEMM->gather only)

  const int nt = cdiv_i(n, 64);
  const int nb = cdiv_i(n, SCAN_B);
  const float inv_n = 1.f / (float)n;

  // ---- degrees, norms, CSR build ----
  hipMemsetAsync(outnorm, 0, (size_t)n * sizeof(float), stream);
  hipMemsetAsync(cnt, 0, (size_t)n * sizeof(int), stream);
  hipMemsetAsync(bnsum, 0, 512 * sizeof(float), stream);
  k_cnt2<<<cdiv_i(E, 1024), 256, 0, stream>>>(src, dst, outnorm, cnt, rank, E);
  k_scan_a<<<nb, SCAN_B, 0, stream>>>(cnt, bsum, n);
  k_scan_b<<<1, 512, 0, stream>>>(bsum, nb, rowptr + n, E);
  k_scan_c<<<nb, SCAN_B, 0, stream>>>(cnt, bsum, rowptr, n);
  k_norm2<<<cdiv_i(n, 256), 256, 0, stream>>>(outnorm, cnt, innorm, invind, n);
  k_fill2<<<cdiv_i(E, 1024), 256, 0, stream>>>(src, dst, rowptr, rank, csr, E);

  // ---- encoder MLP (enc3 -> bf16) ----
  k_gemm_mfma<128,4,1,0,0,0,0><<<dim3(nt,1), 256, 0, stream>>>(features, encW1, encb1, nullptr, hbuf, n, 64);
  k_gemm_mfma<64, 2,1,0,0,0,0><<<dim3(nt,1), 256, 0, stream>>>(hbuf, encW2, encb2, nullptr, nbhw, n, 32);
  k_gemm_mfma<32, 4,0,0,0,1,0><<<dim3(nt,2), 256, 0, stream>>>(nbhw, encW3, encb3, nullptr, (float*)enc_bf, n, 128);

  // ---- layer 0 (conv reads bf16 enc out) ----
  k_gemm_mfma<128,4,0,0,1,1,1><<<dim3(nt,1), 256, 0, stream>>>((const float*)enc_bf, W0, nullptr, outnorm, (float*)hw_bf, n, 64);
  k_gather_bf<<<cdiv_i(n, 4), 256, 0, stream>>>(hw_bf, rowptr, csr, agg, n);
  k_bnstats<<<512, 256, 0, stream>>>(agg, innorm, b0, bnsum, bnsq, n);
  k_post<<<cdiv_i(n * 64, 256), 256, 0, stream>>>(agg, innorm, b0, bnsum, bnsq, gamma, beta, inv_n,
                                                  nullptr, hbuf, h_bf, n * 64);

  // ---- layers 1..3 ----
  for (int i = 1; i < 4; ++i){
    const float* Wi = Wrest + (size_t)(i - 1) * 64 * 64;
    const float* bi = brest + (size_t)(i - 1) * 64;
    // neighbor sum from bf16 shadow of h
    k_gather_bf<<<cdiv_i(n, 4), 256, 0, stream>>>(h_bf, rowptr, csr, nbhw, n);
    // fused attention gate + update
    k_att<<<nt, 256, 0, stream>>>(hbuf, nbhw, invind, attW1, attb1, attW2, attb2, n);
    // conv: hw_bf = bf16((h*outnorm)@Wi); gather; stats; post (+res)
    k_gemm_mfma<64,4,0,0,1,1,0><<<dim3(nt,1), 256, 0, stream>>>(hbuf, Wi, nullptr, outnorm, (float*)hw_bf, n, 64);
    k_gather_bf<<<cdiv_i(n, 4), 256, 0, stream>>>(hw_bf, rowptr, csr, agg, n);
    k_bnstats<<<512, 256, 0, stream>>>(agg, innorm, bi, bnsum + i * 64, bnsq + i * 64, n);
    k_post<<<cdiv_i(n * 64, 256), 256, 0, stream>>>(agg, innorm, bi, bnsum + i * 64, bnsq + i * 64,
                                                    gamma + i * 64, beta + i * 64, inv_n,
                                                    hbuf, hbuf, (i < 3) ? h_bf : nullptr, n * 64);
  }

  // ---- classifier ----
  k_gemm_mfma<64,1,0,0,0,0,0><<<dim3(nt,1), 256, 0, stream>>>(hbuf, fcW, fcb, nullptr, out, n, 16);
}

// Round 11
// 874.110 us; speedup vs baseline: 1.6454x; 1.2967x over previous
//
#include <hip/hip_runtime.h>
#include <hip/hip_bf16.h>
#include <math.h>

// EnhancedResGCN forward. N=100000, E=1600000, IN=128, H=64, C=16, L=4.
// Round 11: row-tile-local megafusion. k_enc = enc1+enc2+enc3+L0conv (4 MFMA
// stages via LDS). k_attconv = attention+conv GEMM. k_postfc = BN-post+FC.
// nb gathers bf16 out; gathers unroll-4. 35 -> 28 dispatches, -290MB traffic.

#define EPS_BN 1e-5f

static inline int cdiv_i(int a, int b){ return (a + b - 1) / b; }

typedef __attribute__((ext_vector_type(8))) short bf16x8;
typedef __attribute__((ext_vector_type(4))) float f32x4;

__device__ inline short f2bf(float f){
  unsigned int u = __builtin_bit_cast(unsigned int, f);
  u += 0x7FFFu + ((u >> 16) & 1u);          // round-to-nearest-even
  return (short)(u >> 16);
}
__device__ inline float bf2f(unsigned short u){
  unsigned int x = ((unsigned int)u) << 16;
  return __builtin_bit_cast(float, x);
}

// pack a KxN row-major fp32 weight into MFMA B-fragment order (bf16) in LDS.
// layout: WP[((kstep*NF+nf)*4+kg)*128 + c*8 + j], k = kstep*32+kg*8+j, col = nf*16+c
__device__ inline void pack_w_lds(const float* __restrict__ W, short* WP, int K, int N){
  int NF = N >> 4;
  int items = (K >> 5) * NF * 64;
  for (int i = threadIdx.x; i < items; i += 256){
    int c  = i & 15;
    int kg = (i >> 4) & 3;
    int t2 = i >> 6;
    int nf = t2 % NF, kstep = t2 / NF;
    short* d = &WP[((kstep * NF + nf) * 4 + kg) * 128 + c * 8];
#pragma unroll
    for (int j = 0; j < 8; ++j){
      int k = kstep * 32 + kg * 8 + j;
      d[j] = f2bf(W[(size_t)k * N + nf * 16 + c]);
    }
  }
}
__device__ inline bf16x8 wfrag(const short* WP, int NF, int kstep, int nf, int lgrp, int lrow){
  return *reinterpret_cast<const bf16x8*>(&WP[((kstep * NF + nf) * 4 + lgrp) * 128 + lrow * 8]);
}

// ---------------- degree count + per-edge rank, 4 edges/thread ----------------
__global__ void k_cnt2(const int* __restrict__ src, const int* __restrict__ dst,
                       float* __restrict__ outd, int* __restrict__ cnt,
                       int* __restrict__ rank, int E){
  int base = blockIdx.x * (blockDim.x * 4) + threadIdx.x;
#pragma unroll
  for (int j = 0; j < 4; ++j){
    int e = base + j * 256;
    if (e < E){
      atomicAdd(&outd[src[e]], 1.f);
      rank[e] = atomicAdd(&cnt[dst[e]], 1);
    }
  }
}

__global__ void k_norm2(float* __restrict__ outn, const int* __restrict__ cnt,
                        float* __restrict__ innorm, float* __restrict__ invind, int n){
  int i = blockIdx.x * blockDim.x + threadIdx.x;
  if (i < n){
    float od = fmaxf(outn[i], 1.f);
    float id = fmaxf((float)cnt[i], 1.f);
    outn[i]   = rsqrtf(od);
    innorm[i] = rsqrtf(id);
    invind[i] = 1.f / id;
  }
}

// ---------------- exclusive scan of cnt[n] -> rowptr ----------------
#define SCAN_B 256
__global__ void k_scan_a(const int* __restrict__ cnt, int* __restrict__ bsum, int n){
  __shared__ int sm[SCAN_B];
  int i = blockIdx.x * SCAN_B + threadIdx.x;
  sm[threadIdx.x] = (i < n) ? cnt[i] : 0;
  __syncthreads();
  for (int s = SCAN_B / 2; s; s >>= 1){
    if (threadIdx.x < s) sm[threadIdx.x] += sm[threadIdx.x + s];
    __syncthreads();
  }
  if (threadIdx.x == 0) bsum[blockIdx.x] = sm[0];
}

__global__ void k_scan_b(int* __restrict__ bsum, int nb, int* __restrict__ rowptr_n, int E){
  __shared__ int sm[512];
  int t = threadIdx.x;
  int orig = (t < nb) ? bsum[t] : 0;
  sm[t] = orig;
  __syncthreads();
  for (int off = 1; off < 512; off <<= 1){
    int v = (t >= off) ? sm[t - off] : 0;
    __syncthreads();
    sm[t] += v;
    __syncthreads();
  }
  if (t < nb) bsum[t] = sm[t] - orig;
  if (t == 0) *rowptr_n = E;
}

__global__ void k_scan_c(const int* __restrict__ cnt, const int* __restrict__ bsum,
                         int* __restrict__ rowptr, int n){
  __shared__ int sm[SCAN_B];
  int i = blockIdx.x * SCAN_B + threadIdx.x;
  int orig = (i < n) ? cnt[i] : 0;
  sm[threadIdx.x] = orig;
  __syncthreads();
  for (int off = 1; off < SCAN_B; off <<= 1){
    int v = (threadIdx.x >= off) ? sm[threadIdx.x - off] : 0;
    __syncthreads();
    sm[threadIdx.x] += v;
    __syncthreads();
  }
  if (i < n) rowptr[i] = sm[threadIdx.x] - orig + bsum[blockIdx.x];
}

__global__ void k_fill2(const int* __restrict__ src, const int* __restrict__ dst,
                        const int* __restrict__ rowptr, const int* __restrict__ rank,
                        int* __restrict__ csr, int E){
  int base = blockIdx.x * (blockDim.x * 4) + threadIdx.x;
#pragma unroll
  for (int j = 0; j < 4; ++j){
    int e = base + j * 256;
    if (e < E) csr[rowptr[dst[e]] + rank[e]] = src[e];
  }
}

// ---------------- fused encoder + layer-0 conv: 4 chained MFMA stages ----------------
// st1: [64][72] bf16 (stride 144B), st2: [64][40], st3 aliases st1 as [64][136].
__global__ __launch_bounds__(256) void k_enc(
    const float* __restrict__ features,
    const float* __restrict__ W1, const float* __restrict__ b1,
    const float* __restrict__ W2, const float* __restrict__ b2,
    const float* __restrict__ W3, const float* __restrict__ b3,
    const float* __restrict__ W0, const float* __restrict__ outnorm,
    unsigned short* __restrict__ hw_bf, int n)
{
  __shared__ short WP1[8192];   // 128x64 enc_W1, later re-packed with W0
  __shared__ short WP2[2048];   // 64x32
  __shared__ short WP3[4096];   // 32x128
  __shared__ short stA[9216];   // st1 [64][72] / st3 [64][136]
  __shared__ short st2[2560];   // [64][40]

  const int tid = threadIdx.x, wave = tid >> 6, lane = tid & 63;
  const int lrow = lane & 15, lgrp = lane >> 4;
  const int row0 = blockIdx.x * 64;
  const int arow = row0 + wave * 16 + lrow;
  const bool rok = arow < n;

  pack_w_lds(W1, WP1, 128, 64);
  pack_w_lds(W2, WP2, 64, 32);
  pack_w_lds(W3, WP3, 32, 128);
  __syncthreads();

  // stage 1: h1 = relu(features @ W1 + b1)  (K=128, NF=4)
  {
    f32x4 acc[4] = {};
#pragma unroll
    for (int kstep = 0; kstep < 4; ++kstep){
      bf16x8 a;
      if (rok){
        const float* p = features + (size_t)arow * 128 + kstep * 32 + lgrp * 8;
        float4 v0 = *reinterpret_cast<const float4*>(p);
        float4 v1 = *reinterpret_cast<const float4*>(p + 4);
        a[0]=f2bf(v0.x); a[1]=f2bf(v0.y); a[2]=f2bf(v0.z); a[3]=f2bf(v0.w);
        a[4]=f2bf(v1.x); a[5]=f2bf(v1.y); a[6]=f2bf(v1.z); a[7]=f2bf(v1.w);
      } else {
#pragma unroll
        for (int j = 0; j < 8; ++j) a[j] = 0;
      }
#pragma unroll
      for (int nf = 0; nf < 4; ++nf)
        acc[nf] = __builtin_amdgcn_mfma_f32_16x16x32_bf16(a, wfrag(WP1,4,kstep,nf,lgrp,lrow), acc[nf], 0,0,0);
    }
#pragma unroll
    for (int nf = 0; nf < 4; ++nf){
      float bv = b1[nf * 16 + lrow];
#pragma unroll
      for (int r = 0; r < 4; ++r)
        stA[(wave*16 + lgrp*4 + r) * 72 + nf*16 + lrow] = f2bf(fmaxf(acc[nf][r] + bv, 0.f));
    }
  }
  __syncthreads();

  pack_w_lds(W0, WP1, 128, 64);      // re-pack W0 over enc_W1's slot

  // stage 2: h2 = relu(h1 @ W2 + b2)  (K=64, NF=2)
  {
    f32x4 acc[2] = {};
#pragma unroll
    for (int kstep = 0; kstep < 2; ++kstep){
      bf16x8 a = *reinterpret_cast<const bf16x8*>(&stA[(wave*16 + lrow) * 72 + kstep*32 + lgrp*8]);
#pragma unroll
      for (int nf = 0; nf < 2; ++nf)
        acc[nf] = __builtin_amdgcn_mfma_f32_16x16x32_bf16(a, wfrag(WP2,2,kstep,nf,lgrp,lrow), acc[nf], 0,0,0);
    }
#pragma unroll
    for (int nf = 0; nf < 2; ++nf){
      float bv = b2[nf * 16 + lrow];
#pragma unroll
      for (int r = 0; r < 4; ++r)
        st2[(wave*16 + lgrp*4 + r) * 40 + nf*16 + lrow] = f2bf(fmaxf(acc[nf][r] + bv, 0.f));
    }
  }
  __syncthreads();

  // stage 3: enc = h2 @ W3 + b3  (K=32, NF=8) -> st3 (aliases stA, stride 136)
  {
    f32x4 acc[8] = {};
    bf16x8 a = *reinterpret_cast<const bf16x8*>(&st2[(wave*16 + lrow) * 40 + lgrp*8]);
#pragma unroll
    for (int nf = 0; nf < 8; ++nf)
      acc[nf] = __builtin_amdgcn_mfma_f32_16x16x32_bf16(a, wfrag(WP3,8,0,nf,lgrp,lrow), acc[nf], 0,0,0);
    __syncthreads();   // all stage-2 reads of stA done before overwrite
#pragma unroll
    for (int nf = 0; nf < 8; ++nf){
      float bv = b3[nf * 16 + lrow];
#pragma unroll
      for (int r = 0; r < 4; ++r)
        stA[(wave*16 + lgrp*4 + r) * 136 + nf*16 + lrow] = f2bf(acc[nf][r] + bv);
    }
  }
  __syncthreads();

  // stage 4: hw = (enc * outnorm) @ W0  (K=128, NF=4) -> bf16 global
  {
    const float rs = rok ? outnorm[arow] : 0.f;
    f32x4 acc[4] = {};
#pragma unroll
    for (int kstep = 0; kstep < 4; ++kstep){
      bf16x8 raw = *reinterpret_cast<const bf16x8*>(&stA[(wave*16 + lrow) * 136 + kstep*32 + lgrp*8]);
      bf16x8 a;
#pragma unroll
      for (int j = 0; j < 8; ++j) a[j] = f2bf(bf2f((unsigned short)raw[j]) * rs);
#pragma unroll
      for (int nf = 0; nf < 4; ++nf)
        acc[nf] = __builtin_amdgcn_mfma_f32_16x16x32_bf16(a, wfrag(WP1,4,kstep,nf,lgrp,lrow), acc[nf], 0,0,0);
    }
#pragma unroll
    for (int nf = 0; nf < 4; ++nf){
#pragma unroll
      for (int r = 0; r < 4; ++r){
        int orow = row0 + wave*16 + lgrp*4 + r;
        if (orow < n) hw_bf[(size_t)orow * 64 + nf*16 + lrow] = (unsigned short)f2bf(acc[nf][r]);
      }
    }
  }
}

// ---------------- fused attention + conv GEMM ----------------
__global__ __launch_bounds__(256) void k_attconv(
    float* __restrict__ h, const unsigned short* __restrict__ nb_bf,
    const float* __restrict__ invind, const float* __restrict__ outnorm,
    const float* __restrict__ W1, const float* __restrict__ b1,
    const float* __restrict__ W2, const float* __restrict__ b2,
    const float* __restrict__ Wi, unsigned short* __restrict__ hw_bf, int n)
{
  __shared__ short WPA[8192];   // att W1 128x64
  __shared__ short WPC[4096];   // conv Wi 64x64
  __shared__ short ht[64 * 72]; // post-attention h tile, bf16

  const int tid = threadIdx.x, wave = tid >> 6, lane = tid & 63;
  const int lrow = lane & 15, lgrp = lane >> 4;
  const int row0 = blockIdx.x * 64;
  const int arow = row0 + wave * 16 + lrow;
  const bool rok = arow < n;

  pack_w_lds(W1, WPA, 128, 64);
  pack_w_lds(Wi, WPC, 64, 64);
  __syncthreads();

  // ---- attention phase: v = relu([h | nb*iv] @ W1 + b1) ----
  const float iv = rok ? invind[arow] : 0.f;
  f32x4 acc[4];
#pragma unroll
  for (int nf = 0; nf < 4; ++nf) acc[nf] = (f32x4){0.f,0.f,0.f,0.f};

#pragma unroll
  for (int kstep = 0; kstep < 4; ++kstep){
    bf16x8 a;
    if (rok){
      if (kstep < 2){
        const float* p = h + (size_t)arow * 64 + kstep * 32 + lgrp * 8;
        float4 v0 = *reinterpret_cast<const float4*>(p);
        float4 v1 = *reinterpret_cast<const float4*>(p + 4);
        a[0]=f2bf(v0.x); a[1]=f2bf(v0.y); a[2]=f2bf(v0.z); a[3]=f2bf(v0.w);
        a[4]=f2bf(v1.x); a[5]=f2bf(v1.y); a[6]=f2bf(v1.z); a[7]=f2bf(v1.w);
      } else {
        const unsigned short* p = nb_bf + (size_t)arow * 64 + (kstep & 1) * 32 + lgrp * 8;
        bf16x8 raw = *reinterpret_cast<const bf16x8*>(p);
#pragma unroll
        for (int j = 0; j < 8; ++j) a[j] = f2bf(bf2f((unsigned short)raw[j]) * iv);
      }
    } else {
#pragma unroll
      for (int j = 0; j < 8; ++j) a[j] = 0;
    }
#pragma unroll
    for (int nf = 0; nf < 4; ++nf)
      acc[nf] = __builtin_amdgcn_mfma_f32_16x16x32_bf16(a, wfrag(WPA,4,kstep,nf,lgrp,lrow), acc[nf], 0,0,0);
  }

  // gate + update; stash h_new tile in LDS for the conv phase
  const float w2l[4] = {W2[lrow], W2[16 + lrow], W2[32 + lrow], W2[48 + lrow]};
  const float b2v = b2[0];
#pragma unroll
  for (int r = 0; r < 4; ++r){
    int orow = row0 + wave*16 + lgrp*4 + r;
    float p = 0.f;
#pragma unroll
    for (int nf = 0; nf < 4; ++nf)
      p += fmaxf(acc[nf][r] + b1[nf * 16 + lrow], 0.f) * w2l[nf];
    p += __shfl_xor(p, 1); p += __shfl_xor(p, 2);
    p += __shfl_xor(p, 4); p += __shfl_xor(p, 8);
    short h0 = 0, h1v = 0, h2v = 0, h3v = 0;
    if (orow < n){
      float a = 1.f / (1.f + expf(-(p + b2v)));
      float ivr = invind[orow];
      const unsigned short* np = nb_bf + (size_t)orow * 64 + lrow * 4;
      float4 hv = *reinterpret_cast<float4*>(&h[(size_t)orow * 64 + lrow * 4]);
      hv.x += a * bf2f(np[0]) * ivr; hv.y += a * bf2f(np[1]) * ivr;
      hv.z += a * bf2f(np[2]) * ivr; hv.w += a * bf2f(np[3]) * ivr;
      *reinterpret_cast<float4*>(&h[(size_t)orow * 64 + lrow * 4]) = hv;
      h0 = f2bf(hv.x); h1v = f2bf(hv.y); h2v = f2bf(hv.z); h3v = f2bf(hv.w);
    }
    short* d = &ht[(wave*16 + lgrp*4 + r) * 72 + lrow * 4];
    d[0] = h0; d[1] = h1v; d[2] = h2v; d[3] = h3v;
  }
  __syncthreads();

  // ---- conv phase: hw = (h_new * outnorm) @ Wi  (K=64, NF=4) ----
  {
    const float rs = rok ? outnorm[arow] : 0.f;
    f32x4 cacc[4];
#pragma unroll
    for (int nf = 0; nf < 4; ++nf) cacc[nf] = (f32x4){0.f,0.f,0.f,0.f};
#pragma unroll
    for (int kstep = 0; kstep < 2; ++kstep){
      bf16x8 raw = *reinterpret_cast<const bf16x8*>(&ht[(wave*16 + lrow) * 72 + kstep*32 + lgrp*8]);
      bf16x8 a;
#pragma unroll
      for (int j = 0; j < 8; ++j) a[j] = f2bf(bf2f((unsigned short)raw[j]) * rs);
#pragma unroll
      for (int nf = 0; nf < 4; ++nf)
        cacc[nf] = __builtin_amdgcn_mfma_f32_16x16x32_bf16(a, wfrag(WPC,4,kstep,nf,lgrp,lrow), cacc[nf], 0,0,0);
    }
#pragma unroll
    for (int nf = 0; nf < 4; ++nf){
#pragma unroll
      for (int r = 0; r < 4; ++r){
        int orow = row0 + wave*16 + lgrp*4 + r;
        if (orow < n) hw_bf[(size_t)orow * 64 + nf*16 + lrow] = (unsigned short)f2bf(cacc[nf][r]);
      }
    }
  }
}

// ---------------- CSR gather (bf16 in): OBF=1 -> bf16 out, else fp32 ----------------
template<int OBF>
__global__ void k_gather(const unsigned short* __restrict__ x,
                         const int* __restrict__ rowptr, const int* __restrict__ csr,
                         void* __restrict__ outv, int n){
  int node = blockIdx.x * 4 + (threadIdx.x >> 6);
  int f = threadIdx.x & 63;
  if (node >= n) return;
  int beg = rowptr[node], end = rowptr[node + 1];
  float a0 = 0.f, a1 = 0.f, a2 = 0.f, a3 = 0.f;
  int e = beg;
  for (; e + 3 < end; e += 4){
    int s0 = csr[e], s1 = csr[e+1], s2 = csr[e+2], s3 = csr[e+3];
    a0 += bf2f(x[(size_t)s0 * 64 + f]);
    a1 += bf2f(x[(size_t)s1 * 64 + f]);
    a2 += bf2f(x[(size_t)s2 * 64 + f]);
    a3 += bf2f(x[(size_t)s3 * 64 + f]);
  }
  for (; e < end; ++e) a0 += bf2f(x[(size_t)csr[e] * 64 + f]);
  float s = (a0 + a1) + (a2 + a3);
  if (OBF) ((unsigned short*)outv)[(size_t)node * 64 + f] = (unsigned short)f2bf(s);
  else     ((float*)outv)[(size_t)node * 64 + f] = s;
}

// ---------------- BatchNorm stats over z = agg*in_norm + b ----------------
__global__ void k_bnstats(const float* __restrict__ agg, const float* __restrict__ innorm,
                          const float* __restrict__ b, float* __restrict__ sum,
                          float* __restrict__ sumsq, int n){
  __shared__ float s1[4][64], s2[4][64];
  int f = threadIdx.x & 63, g = threadIdx.x >> 6;
  float bf = b[f];
  float a1 = 0.f, a2 = 0.f;
  for (int row = blockIdx.x * 4 + g; row < n; row += gridDim.x * 4){
    float z = agg[(size_t)row * 64 + f] * innorm[row] + bf;
    a1 += z; a2 += z * z;
  }
  s1[g][f] = a1; s2[g][f] = a2;
  __syncthreads();
  if (threadIdx.x < 64){
    atomicAdd(&sum[f],   s1[0][f] + s1[1][f] + s1[2][f] + s1[3][f]);
    atomicAdd(&sumsq[f], s2[0][f] + s2[1][f] + s2[2][f] + s2[3][f]);
  }
}

// ---------------- epilogue (layers 0-2): h = relu(BN(..) [+hres]); bf16 shadow ----------------
__global__ void k_post(const float* __restrict__ agg, const float* __restrict__ innorm,
                       const float* __restrict__ b, const float* __restrict__ bnsum,
                       const float* __restrict__ bnsq, const float* __restrict__ gamma,
                       const float* __restrict__ beta, float inv_n,
                       const float* __restrict__ hres,
                       float* __restrict__ hout, unsigned short* __restrict__ hbf, int n64){
  int i = blockIdx.x * blockDim.x + threadIdx.x;
  if (i >= n64) return;
  int f = i & 63, row = i >> 6;
  float mu  = bnsum[f] * inv_n;
  float var = bnsq[f] * inv_n - mu * mu;
  float sc  = gamma[f] * rsqrtf(var + EPS_BN);
  float sh  = beta[f] - mu * sc;
  float z = agg[i] * innorm[row] + b[f];
  z = z * sc + sh;
  if (hres) z += hres[i];
  float r = fmaxf(z, 0.f);
  hout[i] = r;
  hbf[i] = (unsigned short)f2bf(r);
}

// ---------------- layer-3 epilogue fused with FC classifier ----------------
__global__ __launch_bounds__(256) void k_postfc(
    const float* __restrict__ agg, const float* __restrict__ innorm,
    const float* __restrict__ b, const float* __restrict__ bnsum,
    const float* __restrict__ bnsq, const float* __restrict__ gamma,
    const float* __restrict__ beta, float inv_n,
    const float* __restrict__ hres, const float* __restrict__ fcW,
    const float* __restrict__ fcb, float* __restrict__ out, int n)
{
  __shared__ short hb[64 * 72];
  __shared__ short WPF[1024];   // 64x16

  const int tid = threadIdx.x, wave = tid >> 6, lane = tid & 63;
  const int lrow = lane & 15, lgrp = lane >> 4;
  const int row0 = blockIdx.x * 64;

  pack_w_lds(fcW, WPF, 64, 16);

  // BN epilogue into LDS (bf16), h never leaves the block
#pragma unroll
  for (int j = 0; j < 16; ++j){
    int idx = j * 256 + tid;          // 0..4095 = 64 rows x 64 feats
    int row = idx >> 6, f = idx & 63;
    int grow = row0 + row;
    float r = 0.f;
    if (grow < n){
      float mu  = bnsum[f] * inv_n;
      float var = bnsq[f] * inv_n - mu * mu;
      float sc  = gamma[f] * rsqrtf(var + EPS_BN);
      float sh  = beta[f] - mu * sc;
      float z = agg[(size_t)grow * 64 + f] * innorm[grow] + b[f];
      z = z * sc + sh + hres[(size_t)grow * 64 + f];
      r = fmaxf(z, 0.f);
    }
    hb[row * 72 + f] = f2bf(r);
  }
  __syncthreads();

  // FC: out = h @ fcW + fcb  (K=64, NF=1, nout=16)
  f32x4 acc = (f32x4){0.f,0.f,0.f,0.f};
#pragma unroll
  for (int kstep = 0; kstep < 2; ++kstep){
    bf16x8 a = *reinterpret_cast<const bf16x8*>(&hb[(wave*16 + lrow) * 72 + kstep*32 + lgrp*8]);
    acc = __builtin_amdgcn_mfma_f32_16x16x32_bf16(a, wfrag(WPF,1,kstep,0,lgrp,lrow), acc, 0,0,0);
  }
  float bv = fcb[lrow];
#pragma unroll
  for (int r = 0; r < 4; ++r){
    int orow = row0 + wave*16 + lgrp*4 + r;
    if (orow < n) out[(size_t)orow * 16 + lrow] = acc[r] + bv;
  }
}

extern "C" void kernel_launch(void* const* d_in, const int* in_sizes, int n_in,
                              void* d_out, int out_size, void* d_ws, size_t ws_size,
                              hipStream_t stream) {
  const float* features = (const float*)d_in[0];
  const int*   src      = (const int*)d_in[1];
  const int*   dst      = (const int*)d_in[2];
  const float* encW1 = (const float*)d_in[3];  const float* encb1 = (const float*)d_in[4];
  const float* encW2 = (const float*)d_in[5];  const float* encb2 = (const float*)d_in[6];
  const float* encW3 = (const float*)d_in[7];  const float* encb3 = (const float*)d_in[8];
  const float* attW1 = (const float*)d_in[9];  const float* attb1 = (const float*)d_in[10];
  const float* attW2 = (const float*)d_in[11]; const float* attb2 = (const float*)d_in[12];
  const float* W0    = (const float*)d_in[13]; const float* b0    = (const float*)d_in[14];
  const float* Wrest = (const float*)d_in[15]; const float* brest = (const float*)d_in[16];
  const float* gamma = (const float*)d_in[17]; const float* beta  = (const float*)d_in[18];
  const float* fcW   = (const float*)d_in[19]; const float* fcb   = (const float*)d_in[20];
  float* out = (float*)d_out;

  const int n = in_sizes[0] / 128;   // 100000
  const int E = in_sizes[1];         // 1600000

  // float workspace
  float* ws      = (float*)d_ws;
  float* agg     = ws;                               // N*64 f32
  unsigned short* h_bf = (unsigned short*)(ws + (size_t)n * 64);   // N*64 bf16
  float* hbuf    = ws + (size_t)n * 128;             // N*64 f32 (h)
  float* nbhw    = hbuf + (size_t)n * 64;            // N*64 f32 scratch region
  float* outnorm = nbhw + (size_t)n * 64;
  float* innorm  = outnorm + n;
  float* invind  = innorm + n;
  float* bnsum   = invind + n;                       // 4 x 64
  float* bnsq    = bnsum + 256;                      // 4 x 64
  // int workspace (CSR)
  int* cnt    = (int*)(bnsq + 256);
  int* rowptr = cnt + n;                             // n+1
  int* csr    = rowptr + n + 1;                      // E
  int* bsum   = csr + E;                             // 512
  // sequential-lifetime aliases inside nbhw
  int* rank = (int*)nbhw;                            // E ints (dead after fill2)
  unsigned short* nb_bf = (unsigned short*)nbhw;                   // N*64 bf16
  unsigned short* hw_bf = (unsigned short*)(nbhw + (size_t)n * 32);// N*64 bf16

  const int nt = cdiv_i(n, 64);
  const int nb = cdiv_i(n, SCAN_B);
  const float inv_n = 1.f / (float)n;

  // ---- degrees, norms, CSR build ----
  hipMemsetAsync(outnorm, 0, (size_t)n * sizeof(float), stream);
  hipMemsetAsync(cnt, 0, (size_t)n * sizeof(int), stream);
  hipMemsetAsync(bnsum, 0, 512 * sizeof(float), stream);
  k_cnt2<<<cdiv_i(E, 1024), 256, 0, stream>>>(src, dst, outnorm, cnt, rank, E);
  k_scan_a<<<nb, SCAN_B, 0, stream>>>(cnt, bsum, n);
  k_scan_b<<<1, 512, 0, stream>>>(bsum, nb, rowptr + n, E);
  k_scan_c<<<nb, SCAN_B, 0, stream>>>(cnt, bsum, rowptr, n);
  k_norm2<<<cdiv_i(n, 256), 256, 0, stream>>>(outnorm, cnt, innorm, invind, n);
  k_fill2<<<cdiv_i(E, 1024), 256, 0, stream>>>(src, dst, rowptr, rank, csr, E);

  // ---- fused encoder + layer-0 conv ----
  k_enc<<<nt, 256, 0, stream>>>(features, encW1, encb1, encW2, encb2, encW3, encb3,
                                W0, outnorm, hw_bf, n);
  k_gather<0><<<cdiv_i(n, 4), 256, 0, stream>>>(hw_bf, rowptr, csr, agg, n);
  k_bnstats<<<512, 256, 0, stream>>>(agg, innorm, b0, bnsum, bnsq, n);
  k_post<<<cdiv_i(n * 64, 256), 256, 0, stream>>>(agg, innorm, b0, bnsum, bnsq, gamma, beta, inv_n,
                                                  nullptr, hbuf, h_bf, n * 64);

  // ---- layers 1..3 ----
  for (int i = 1; i < 4; ++i){
    const float* Wi = Wrest + (size_t)(i - 1) * 64 * 64;
    const float* bi = brest + (size_t)(i - 1) * 64;
    k_gather<1><<<cdiv_i(n, 4), 256, 0, stream>>>(h_bf, rowptr, csr, nb_bf, n);
    k_attconv<<<nt, 256, 0, stream>>>(hbuf, nb_bf, invind, outnorm,
                                      attW1, attb1, attW2, attb2, Wi, hw_bf, n);
    k_gather<0><<<cdiv_i(n, 4), 256, 0, stream>>>(hw_bf, rowptr, csr, agg, n);
    k_bnstats<<<512, 256, 0, stream>>>(agg, innorm, bi, bnsum + i * 64, bnsq + i * 64, n);
    if (i < 3){
      k_post<<<cdiv_i(n * 64, 256), 256, 0, stream>>>(agg, innorm, bi, bnsum + i * 64, bnsq + i * 64,
                                                      gamma + i * 64, beta + i * 64, inv_n,
                                                      hbuf, hbuf, h_bf, n * 64);
    } else {
      k_postfc<<<nt, 256, 0, stream>>>(agg, innorm, bi, bnsum + i * 64, bnsq + i * 64,
                                       gamma + i * 64, beta + i * 64, inv_n,
                                       hbuf, fcW, fcb, out, n);
    }
  }
}

// Round 12
// 788.809 us; speedup vs baseline: 1.8233x; 1.1081x over previous
//
#include <hip/hip_runtime.h>
#include <hip/hip_bf16.h>
#include <math.h>

// EnhancedResGCN forward. N=100000, E=1600000, IN=128, H=64, C=16, L=4.
// Round 12: BN stats fused into agg-gather (2048-block full-occupancy grid-stride,
// plain per-block partials + tiny reduce; no atomics), norm folded into scan_a,
// merged memset, float4 k_post. 28 -> 25 dispatches.

#define EPS_BN 1e-5f
#define GS_BLOCKS 2048

static inline int cdiv_i(int a, int b){ return (a + b - 1) / b; }

typedef __attribute__((ext_vector_type(8))) short bf16x8;
typedef __attribute__((ext_vector_type(4))) float f32x4;
typedef __attribute__((ext_vector_type(4))) unsigned short u16x4;

__device__ inline short f2bf(float f){
  unsigned int u = __builtin_bit_cast(unsigned int, f);
  u += 0x7FFFu + ((u >> 16) & 1u);          // round-to-nearest-even
  return (short)(u >> 16);
}
__device__ inline float bf2f(unsigned short u){
  unsigned int x = ((unsigned int)u) << 16;
  return __builtin_bit_cast(float, x);
}

// pack a KxN row-major fp32 weight into MFMA B-fragment order (bf16) in LDS.
__device__ inline void pack_w_lds(const float* __restrict__ W, short* WP, int K, int N){
  int NF = N >> 4;
  int items = (K >> 5) * NF * 64;
  for (int i = threadIdx.x; i < items; i += 256){
    int c  = i & 15;
    int kg = (i >> 4) & 3;
    int t2 = i >> 6;
    int nf = t2 % NF, kstep = t2 / NF;
    short* d = &WP[((kstep * NF + nf) * 4 + kg) * 128 + c * 8];
#pragma unroll
    for (int j = 0; j < 8; ++j){
      int k = kstep * 32 + kg * 8 + j;
      d[j] = f2bf(W[(size_t)k * N + nf * 16 + c]);
    }
  }
}
__device__ inline bf16x8 wfrag(const short* WP, int NF, int kstep, int nf, int lgrp, int lrow){
  return *reinterpret_cast<const bf16x8*>(&WP[((kstep * NF + nf) * 4 + lgrp) * 128 + lrow * 8]);
}

// ---------------- degree count + per-edge rank, 4 edges/thread ----------------
__global__ void k_cnt2(const int* __restrict__ src, const int* __restrict__ dst,
                       float* __restrict__ outd, int* __restrict__ cnt,
                       int* __restrict__ rank, int E){
  int base = blockIdx.x * (blockDim.x * 4) + threadIdx.x;
#pragma unroll
  for (int j = 0; j < 4; ++j){
    int e = base + j * 256;
    if (e < E){
      atomicAdd(&outd[src[e]], 1.f);
      rank[e] = atomicAdd(&cnt[dst[e]], 1);
    }
  }
}

// ---------------- scan stage A + degree norms (merged) ----------------
#define SCAN_B 256
__global__ void k_scan_a(const int* __restrict__ cnt, int* __restrict__ bsum,
                         float* __restrict__ outn, float* __restrict__ innorm,
                         float* __restrict__ invind, int n){
  __shared__ int sm[SCAN_B];
  int i = blockIdx.x * SCAN_B + threadIdx.x;
  int c = (i < n) ? cnt[i] : 0;
  if (i < n){
    float od = fmaxf(outn[i], 1.f);        // outn holds outd here
    float id = fmaxf((float)c, 1.f);
    outn[i]   = rsqrtf(od);
    innorm[i] = rsqrtf(id);
    invind[i] = 1.f / id;
  }
  sm[threadIdx.x] = c;
  __syncthreads();
  for (int s = SCAN_B / 2; s; s >>= 1){
    if (threadIdx.x < s) sm[threadIdx.x] += sm[threadIdx.x + s];
    __syncthreads();
  }
  if (threadIdx.x == 0) bsum[blockIdx.x] = sm[0];
}

__global__ void k_scan_b(int* __restrict__ bsum, int nb, int* __restrict__ rowptr_n, int E){
  __shared__ int sm[512];
  int t = threadIdx.x;
  int orig = (t < nb) ? bsum[t] : 0;
  sm[t] = orig;
  __syncthreads();
  for (int off = 1; off < 512; off <<= 1){
    int v = (t >= off) ? sm[t - off] : 0;
    __syncthreads();
    sm[t] += v;
    __syncthreads();
  }
  if (t < nb) bsum[t] = sm[t] - orig;
  if (t == 0) *rowptr_n = E;
}

__global__ void k_scan_c(const int* __restrict__ cnt, const int* __restrict__ bsum,
                         int* __restrict__ rowptr, int n){
  __shared__ int sm[SCAN_B];
  int i = blockIdx.x * SCAN_B + threadIdx.x;
  int orig = (i < n) ? cnt[i] : 0;
  sm[threadIdx.x] = orig;
  __syncthreads();
  for (int off = 1; off < SCAN_B; off <<= 1){
    int v = (threadIdx.x >= off) ? sm[threadIdx.x - off] : 0;
    __syncthreads();
    sm[threadIdx.x] += v;
    __syncthreads();
  }
  if (i < n) rowptr[i] = sm[threadIdx.x] - orig + bsum[blockIdx.x];
}

__global__ void k_fill2(const int* __restrict__ src, const int* __restrict__ dst,
                        const int* __restrict__ rowptr, const int* __restrict__ rank,
                        int* __restrict__ csr, int E){
  int base = blockIdx.x * (blockDim.x * 4) + threadIdx.x;
#pragma unroll
  for (int j = 0; j < 4; ++j){
    int e = base + j * 256;
    if (e < E) csr[rowptr[dst[e]] + rank[e]] = src[e];
  }
}

// ---------------- fused encoder + layer-0 conv: 4 chained MFMA stages ----------------
__global__ __launch_bounds__(256) void k_enc(
    const float* __restrict__ features,
    const float* __restrict__ W1, const float* __restrict__ b1,
    const float* __restrict__ W2, const float* __restrict__ b2,
    const float* __restrict__ W3, const float* __restrict__ b3,
    const float* __restrict__ W0, const float* __restrict__ outnorm,
    unsigned short* __restrict__ hw_bf, int n)
{
  __shared__ short WP1[8192];   // 128x64 enc_W1, later re-packed with W0
  __shared__ short WP2[2048];   // 64x32
  __shared__ short WP3[4096];   // 32x128
  __shared__ short stA[9216];   // st1 [64][72] / st3 [64][136]
  __shared__ short st2[2560];   // [64][40]

  const int tid = threadIdx.x, wave = tid >> 6, lane = tid & 63;
  const int lrow = lane & 15, lgrp = lane >> 4;
  const int row0 = blockIdx.x * 64;
  const int arow = row0 + wave * 16 + lrow;
  const bool rok = arow < n;

  pack_w_lds(W1, WP1, 128, 64);
  pack_w_lds(W2, WP2, 64, 32);
  pack_w_lds(W3, WP3, 32, 128);
  __syncthreads();

  {
    f32x4 acc[4] = {};
#pragma unroll
    for (int kstep = 0; kstep < 4; ++kstep){
      bf16x8 a;
      if (rok){
        const float* p = features + (size_t)arow * 128 + kstep * 32 + lgrp * 8;
        float4 v0 = *reinterpret_cast<const float4*>(p);
        float4 v1 = *reinterpret_cast<const float4*>(p + 4);
        a[0]=f2bf(v0.x); a[1]=f2bf(v0.y); a[2]=f2bf(v0.z); a[3]=f2bf(v0.w);
        a[4]=f2bf(v1.x); a[5]=f2bf(v1.y); a[6]=f2bf(v1.z); a[7]=f2bf(v1.w);
      } else {
#pragma unroll
        for (int j = 0; j < 8; ++j) a[j] = 0;
      }
#pragma unroll
      for (int nf = 0; nf < 4; ++nf)
        acc[nf] = __builtin_amdgcn_mfma_f32_16x16x32_bf16(a, wfrag(WP1,4,kstep,nf,lgrp,lrow), acc[nf], 0,0,0);
    }
#pragma unroll
    for (int nf = 0; nf < 4; ++nf){
      float bv = b1[nf * 16 + lrow];
#pragma unroll
      for (int r = 0; r < 4; ++r)
        stA[(wave*16 + lgrp*4 + r) * 72 + nf*16 + lrow] = f2bf(fmaxf(acc[nf][r] + bv, 0.f));
    }
  }
  __syncthreads();

  pack_w_lds(W0, WP1, 128, 64);      // re-pack W0 over enc_W1's slot

  {
    f32x4 acc[2] = {};
#pragma unroll
    for (int kstep = 0; kstep < 2; ++kstep){
      bf16x8 a = *reinterpret_cast<const bf16x8*>(&stA[(wave*16 + lrow) * 72 + kstep*32 + lgrp*8]);
#pragma unroll
      for (int nf = 0; nf < 2; ++nf)
        acc[nf] = __builtin_amdgcn_mfma_f32_16x16x32_bf16(a, wfrag(WP2,2,kstep,nf,lgrp,lrow), acc[nf], 0,0,0);
    }
#pragma unroll
    for (int nf = 0; nf < 2; ++nf){
      float bv = b2[nf * 16 + lrow];
#pragma unroll
      for (int r = 0; r < 4; ++r)
        st2[(wave*16 + lgrp*4 + r) * 40 + nf*16 + lrow] = f2bf(fmaxf(acc[nf][r] + bv, 0.f));
    }
  }
  __syncthreads();

  {
    f32x4 acc[8] = {};
    bf16x8 a = *reinterpret_cast<const bf16x8*>(&st2[(wave*16 + lrow) * 40 + lgrp*8]);
#pragma unroll
    for (int nf = 0; nf < 8; ++nf)
      acc[nf] = __builtin_amdgcn_mfma_f32_16x16x32_bf16(a, wfrag(WP3,8,0,nf,lgrp,lrow), acc[nf], 0,0,0);
    __syncthreads();
#pragma unroll
    for (int nf = 0; nf < 8; ++nf){
      float bv = b3[nf * 16 + lrow];
#pragma unroll
      for (int r = 0; r < 4; ++r)
        stA[(wave*16 + lgrp*4 + r) * 136 + nf*16 + lrow] = f2bf(acc[nf][r] + bv);
    }
  }
  __syncthreads();

  {
    const float rs = rok ? outnorm[arow] : 0.f;
    f32x4 acc[4] = {};
#pragma unroll
    for (int kstep = 0; kstep < 4; ++kstep){
      bf16x8 raw = *reinterpret_cast<const bf16x8*>(&stA[(wave*16 + lrow) * 136 + kstep*32 + lgrp*8]);
      bf16x8 a;
#pragma unroll
      for (int j = 0; j < 8; ++j) a[j] = f2bf(bf2f((unsigned short)raw[j]) * rs);
#pragma unroll
      for (int nf = 0; nf < 4; ++nf)
        acc[nf] = __builtin_amdgcn_mfma_f32_16x16x32_bf16(a, wfrag(WP1,4,kstep,nf,lgrp,lrow), acc[nf], 0,0,0);
    }
#pragma unroll
    for (int nf = 0; nf < 4; ++nf){
#pragma unroll
      for (int r = 0; r < 4; ++r){
        int orow = row0 + wave*16 + lgrp*4 + r;
        if (orow < n) hw_bf[(size_t)orow * 64 + nf*16 + lrow] = (unsigned short)f2bf(acc[nf][r]);
      }
    }
  }
}

// ---------------- fused attention + conv GEMM ----------------
__global__ __launch_bounds__(256) void k_attconv(
    float* __restrict__ h, const unsigned short* __restrict__ nb_bf,
    const float* __restrict__ invind, const float* __restrict__ outnorm,
    const float* __restrict__ W1, const float* __restrict__ b1,
    const float* __restrict__ W2, const float* __restrict__ b2,
    const float* __restrict__ Wi, unsigned short* __restrict__ hw_bf, int n)
{
  __shared__ short WPA[8192];   // att W1 128x64
  __shared__ short WPC[4096];   // conv Wi 64x64
  __shared__ short ht[64 * 72]; // post-attention h tile, bf16

  const int tid = threadIdx.x, wave = tid >> 6, lane = tid & 63;
  const int lrow = lane & 15, lgrp = lane >> 4;
  const int row0 = blockIdx.x * 64;
  const int arow = row0 + wave * 16 + lrow;
  const bool rok = arow < n;

  pack_w_lds(W1, WPA, 128, 64);
  pack_w_lds(Wi, WPC, 64, 64);
  __syncthreads();

  const float iv = rok ? invind[arow] : 0.f;
  f32x4 acc[4];
#pragma unroll
  for (int nf = 0; nf < 4; ++nf) acc[nf] = (f32x4){0.f,0.f,0.f,0.f};

#pragma unroll
  for (int kstep = 0; kstep < 4; ++kstep){
    bf16x8 a;
    if (rok){
      if (kstep < 2){
        const float* p = h + (size_t)arow * 64 + kstep * 32 + lgrp * 8;
        float4 v0 = *reinterpret_cast<const float4*>(p);
        float4 v1 = *reinterpret_cast<const float4*>(p + 4);
        a[0]=f2bf(v0.x); a[1]=f2bf(v0.y); a[2]=f2bf(v0.z); a[3]=f2bf(v0.w);
        a[4]=f2bf(v1.x); a[5]=f2bf(v1.y); a[6]=f2bf(v1.z); a[7]=f2bf(v1.w);
      } else {
        const unsigned short* p = nb_bf + (size_t)arow * 64 + (kstep & 1) * 32 + lgrp * 8;
        bf16x8 raw = *reinterpret_cast<const bf16x8*>(p);
#pragma unroll
        for (int j = 0; j < 8; ++j) a[j] = f2bf(bf2f((unsigned short)raw[j]) * iv);
      }
    } else {
#pragma unroll
      for (int j = 0; j < 8; ++j) a[j] = 0;
    }
#pragma unroll
    for (int nf = 0; nf < 4; ++nf)
      acc[nf] = __builtin_amdgcn_mfma_f32_16x16x32_bf16(a, wfrag(WPA,4,kstep,nf,lgrp,lrow), acc[nf], 0,0,0);
  }

  const float w2l[4] = {W2[lrow], W2[16 + lrow], W2[32 + lrow], W2[48 + lrow]};
  const float b2v = b2[0];
#pragma unroll
  for (int r = 0; r < 4; ++r){
    int orow = row0 + wave*16 + lgrp*4 + r;
    float p = 0.f;
#pragma unroll
    for (int nf = 0; nf < 4; ++nf)
      p += fmaxf(acc[nf][r] + b1[nf * 16 + lrow], 0.f) * w2l[nf];
    p += __shfl_xor(p, 1); p += __shfl_xor(p, 2);
    p += __shfl_xor(p, 4); p += __shfl_xor(p, 8);
    short h0 = 0, h1v = 0, h2v = 0, h3v = 0;
    if (orow < n){
      float a = 1.f / (1.f + expf(-(p + b2v)));
      float ivr = invind[orow];
      const unsigned short* np = nb_bf + (size_t)orow * 64 + lrow * 4;
      float4 hv = *reinterpret_cast<float4*>(&h[(size_t)orow * 64 + lrow * 4]);
      hv.x += a * bf2f(np[0]) * ivr; hv.y += a * bf2f(np[1]) * ivr;
      hv.z += a * bf2f(np[2]) * ivr; hv.w += a * bf2f(np[3]) * ivr;
      *reinterpret_cast<float4*>(&h[(size_t)orow * 64 + lrow * 4]) = hv;
      h0 = f2bf(hv.x); h1v = f2bf(hv.y); h2v = f2bf(hv.z); h3v = f2bf(hv.w);
    }
    short* d = &ht[(wave*16 + lgrp*4 + r) * 72 + lrow * 4];
    d[0] = h0; d[1] = h1v; d[2] = h2v; d[3] = h3v;
  }
  __syncthreads();

  {
    const float rs = rok ? outnorm[arow] : 0.f;
    f32x4 cacc[4];
#pragma unroll
    for (int nf = 0; nf < 4; ++nf) cacc[nf] = (f32x4){0.f,0.f,0.f,0.f};
#pragma unroll
    for (int kstep = 0; kstep < 2; ++kstep){
      bf16x8 raw = *reinterpret_cast<const bf16x8*>(&ht[(wave*16 + lrow) * 72 + kstep*32 + lgrp*8]);
      bf16x8 a;
#pragma unroll
      for (int j = 0; j < 8; ++j) a[j] = f2bf(bf2f((unsigned short)raw[j]) * rs);
#pragma unroll
      for (int nf = 0; nf < 4; ++nf)
        cacc[nf] = __builtin_amdgcn_mfma_f32_16x16x32_bf16(a, wfrag(WPC,4,kstep,nf,lgrp,lrow), cacc[nf], 0,0,0);
    }
#pragma unroll
    for (int nf = 0; nf < 4; ++nf){
#pragma unroll
      for (int r = 0; r < 4; ++r){
        int orow = row0 + wave*16 + lgrp*4 + r;
        if (orow < n) hw_bf[(size_t)orow * 64 + nf*16 + lrow] = (unsigned short)f2bf(cacc[nf][r]);
      }
    }
  }
}

// ---------------- nb gather (bf16 in, bf16 out), wave per node ----------------
__global__ void k_gather_nb(const unsigned short* __restrict__ x,
                            const int* __restrict__ rowptr, const int* __restrict__ csr,
                            unsigned short* __restrict__ outv, int n){
  int node = blockIdx.x * 4 + (threadIdx.x >> 6);
  int f = threadIdx.x & 63;
  if (node >= n) return;
  int beg = rowptr[node], end = rowptr[node + 1];
  float a0 = 0.f, a1 = 0.f, a2 = 0.f, a3 = 0.f;
  int e = beg;
  for (; e + 3 < end; e += 4){
    int s0 = csr[e], s1 = csr[e+1], s2 = csr[e+2], s3 = csr[e+3];
    a0 += bf2f(x[(size_t)s0 * 64 + f]);
    a1 += bf2f(x[(size_t)s1 * 64 + f]);
    a2 += bf2f(x[(size_t)s2 * 64 + f]);
    a3 += bf2f(x[(size_t)s3 * 64 + f]);
  }
  for (; e < end; ++e) a0 += bf2f(x[(size_t)csr[e] * 64 + f]);
  outv[(size_t)node * 64 + f] = (unsigned short)f2bf((a0 + a1) + (a2 + a3));
}

// ---------------- agg gather + fused BN partial stats (full-occupancy grid-stride) ----------------
__global__ __launch_bounds__(256) void k_gather_stats(
    const unsigned short* __restrict__ x, const int* __restrict__ rowptr,
    const int* __restrict__ csr, const float* __restrict__ innorm,
    const float* __restrict__ b, float* __restrict__ agg,
    float* __restrict__ p1, float* __restrict__ p2, int n){
  __shared__ float s1[4][64], s2[4][64];
  int g = threadIdx.x >> 6, f = threadIdx.x & 63;
  float bf = b[f];
  float z1 = 0.f, z2 = 0.f;
  for (int node = blockIdx.x * 4 + g; node < n; node += GS_BLOCKS * 4){
    int beg = rowptr[node], end = rowptr[node + 1];
    float a0 = 0.f, a1 = 0.f, a2 = 0.f, a3 = 0.f;
    int e = beg;
    for (; e + 3 < end; e += 4){
      int s0v = csr[e], s1v = csr[e+1], s2v = csr[e+2], s3v = csr[e+3];
      a0 += bf2f(x[(size_t)s0v * 64 + f]);
      a1 += bf2f(x[(size_t)s1v * 64 + f]);
      a2 += bf2f(x[(size_t)s2v * 64 + f]);
      a3 += bf2f(x[(size_t)s3v * 64 + f]);
    }
    for (; e < end; ++e) a0 += bf2f(x[(size_t)csr[e] * 64 + f]);
    float s = (a0 + a1) + (a2 + a3);
    agg[(size_t)node * 64 + f] = s;
    float z = s * innorm[node] + bf;
    z1 += z; z2 += z * z;
  }
  s1[g][f] = z1; s2[g][f] = z2;
  __syncthreads();
  if (threadIdx.x < 64){
    p1[(size_t)blockIdx.x * 64 + f] = s1[0][f] + s1[1][f] + s1[2][f] + s1[3][f];
    p2[(size_t)blockIdx.x * 64 + f] = s2[0][f] + s2[1][f] + s2[2][f] + s2[3][f];
  }
}

// ---------------- reduce partials -> bnsum/bnsq (128 blocks, no atomics) ----------------
__global__ void k_bnred(const float* __restrict__ p1, const float* __restrict__ p2,
                        float* __restrict__ bnsum, float* __restrict__ bnsq){
  __shared__ float sm[256];
  int f = blockIdx.x & 63, stat = blockIdx.x >> 6;
  const float* p = stat ? p2 : p1;
  float a = 0.f;
  for (int i = threadIdx.x; i < GS_BLOCKS; i += 256) a += p[(size_t)i * 64 + f];
  sm[threadIdx.x] = a;
  __syncthreads();
  for (int s = 128; s; s >>= 1){
    if (threadIdx.x < s) sm[threadIdx.x] += sm[threadIdx.x + s];
    __syncthreads();
  }
  if (threadIdx.x == 0) (stat ? bnsq : bnsum)[f] = sm[0];
}

// ---------------- epilogue (layers 0-2): float4, h = relu(BN [+hres]); bf16 shadow ----------------
__global__ void k_post(const float* __restrict__ agg, const float* __restrict__ innorm,
                       const float* __restrict__ b, const float* __restrict__ bnsum,
                       const float* __restrict__ bnsq, const float* __restrict__ gamma,
                       const float* __restrict__ beta, float inv_n,
                       const float* __restrict__ hres,
                       float* __restrict__ hout, unsigned short* __restrict__ hbf, int n16){
  int i = blockIdx.x * blockDim.x + threadIdx.x;   // one per 4 feats
  if (i >= n16) return;
  int row = i >> 4, fq = (i & 15) * 4;
  size_t o = (size_t)row * 64 + fq;
  float inn = innorm[row];
  float4 av = *reinterpret_cast<const float4*>(&agg[o]);
  float4 rv = hres ? *reinterpret_cast<const float4*>(&hres[o]) : (float4){0.f,0.f,0.f,0.f};
  float r[4]; float aa[4] = {av.x, av.y, av.z, av.w}; float rr[4] = {rv.x, rv.y, rv.z, rv.w};
#pragma unroll
  for (int j = 0; j < 4; ++j){
    int f = fq + j;
    float mu  = bnsum[f] * inv_n;
    float var = bnsq[f] * inv_n - mu * mu;
    float sc  = gamma[f] * rsqrtf(var + EPS_BN);
    float sh  = beta[f] - mu * sc;
    float z = aa[j] * inn + b[f];
    z = z * sc + sh + rr[j];
    r[j] = fmaxf(z, 0.f);
  }
  *reinterpret_cast<float4*>(&hout[o]) = (float4){r[0], r[1], r[2], r[3]};
  u16x4 hb;
#pragma unroll
  for (int j = 0; j < 4; ++j) hb[j] = (unsigned short)f2bf(r[j]);
  *reinterpret_cast<u16x4*>(&hbf[o]) = hb;
}

// ---------------- layer-3 epilogue fused with FC classifier ----------------
__global__ __launch_bounds__(256) void k_postfc(
    const float* __restrict__ agg, const float* __restrict__ innorm,
    const float* __restrict__ b, const float* __restrict__ bnsum,
    const float* __restrict__ bnsq, const float* __restrict__ gamma,
    const float* __restrict__ beta, float inv_n,
    const float* __restrict__ hres, const float* __restrict__ fcW,
    const float* __restrict__ fcb, float* __restrict__ out, int n)
{
  __shared__ short hb[64 * 72];
  __shared__ short WPF[1024];   // 64x16

  const int tid = threadIdx.x, wave = tid >> 6, lane = tid & 63;
  const int lrow = lane & 15, lgrp = lane >> 4;
  const int row0 = blockIdx.x * 64;

  pack_w_lds(fcW, WPF, 64, 16);

#pragma unroll
  for (int j = 0; j < 16; ++j){
    int idx = j * 256 + tid;
    int row = idx >> 6, f = idx & 63;
    int grow = row0 + row;
    float r = 0.f;
    if (grow < n){
      float mu  = bnsum[f] * inv_n;
      float var = bnsq[f] * inv_n - mu * mu;
      float sc  = gamma[f] * rsqrtf(var + EPS_BN);
      float sh  = beta[f] - mu * sc;
      float z = agg[(size_t)grow * 64 + f] * innorm[grow] + b[f];
      z = z * sc + sh + hres[(size_t)grow * 64 + f];
      r = fmaxf(z, 0.f);
    }
    hb[row * 72 + f] = f2bf(r);
  }
  __syncthreads();

  f32x4 acc = (f32x4){0.f,0.f,0.f,0.f};
#pragma unroll
  for (int kstep = 0; kstep < 2; ++kstep){
    bf16x8 a = *reinterpret_cast<const bf16x8*>(&hb[(wave*16 + lrow) * 72 + kstep*32 + lgrp*8]);
    acc = __builtin_amdgcn_mfma_f32_16x16x32_bf16(a, wfrag(WPF,1,kstep,0,lgrp,lrow), acc, 0,0,0);
  }
  float bv = fcb[lrow];
#pragma unroll
  for (int r = 0; r < 4; ++r){
    int orow = row0 + wave*16 + lgrp*4 + r;
    if (orow < n) out[(size_t)orow * 16 + lrow] = acc[r] + bv;
  }
}

extern "C" void kernel_launch(void* const* d_in, const int* in_sizes, int n_in,
                              void* d_out, int out_size, void* d_ws, size_t ws_size,
                              hipStream_t stream) {
  const float* features = (const float*)d_in[0];
  const int*   src      = (const int*)d_in[1];
  const int*   dst      = (const int*)d_in[2];
  const float* encW1 = (const float*)d_in[3];  const float* encb1 = (const float*)d_in[4];
  const float* encW2 = (const float*)d_in[5];  const float* encb2 = (const float*)d_in[6];
  const float* encW3 = (const float*)d_in[7];  const float* encb3 = (const float*)d_in[8];
  const float* attW1 = (const float*)d_in[9];  const float* attb1 = (const float*)d_in[10];
  const float* attW2 = (const float*)d_in[11]; const float* attb2 = (const float*)d_in[12];
  const float* W0    = (const float*)d_in[13]; const float* b0    = (const float*)d_in[14];
  const float* Wrest = (const float*)d_in[15]; const float* brest = (const float*)d_in[16];
  const float* gamma = (const float*)d_in[17]; const float* beta  = (const float*)d_in[18];
  const float* fcW   = (const float*)d_in[19]; const float* fcb   = (const float*)d_in[20];
  float* out = (float*)d_out;

  const int n = in_sizes[0] / 128;   // 100000
  const int E = in_sizes[1];         // 1600000

  float* ws      = (float*)d_ws;
  float* agg     = ws;                                             // n*64 f32
  unsigned short* h_bf = (unsigned short*)(ws + (size_t)n * 64);   // n*64 bf16 (= n*32 floats)
  float* p1      = ws + (size_t)n * 96;                            // 2048*64
  float* p2      = p1 + (size_t)GS_BLOCKS * 64;                    // 2048*64
  float* hbuf    = ws + (size_t)n * 128;                           // n*64 f32 (h)
  float* nbhw    = hbuf + (size_t)n * 64;                          // n*64 scratch
  float* outnorm = nbhw + (size_t)n * 64;                          // n  (outd -> out_norm)
  int*   cnt     = (int*)(outnorm + n);                            // n  (contiguous w/ outnorm)
  float* innorm  = (float*)(cnt + n);                              // n
  float* invind  = innorm + n;                                     // n
  float* bnsum   = invind + n;                                     // 4x64
  float* bnsq    = bnsum + 256;                                    // 4x64
  int* rowptr = (int*)(bnsq + 256);                                // n+1
  int* csr    = rowptr + n + 1;                                    // E
  int* bsum   = csr + E;                                           // 512
  // sequential-lifetime aliases inside nbhw
  int* rank = (int*)nbhw;                                          // E ints (dead after fill2)
  unsigned short* nb_bf = (unsigned short*)nbhw;                   // n*64 bf16
  unsigned short* hw_bf = (unsigned short*)(nbhw + (size_t)n * 32);// n*64 bf16

  const int nt = cdiv_i(n, 64);
  const int nb = cdiv_i(n, SCAN_B);
  const float inv_n = 1.f / (float)n;

  // ---- degrees, norms, CSR build ----
  hipMemsetAsync(outnorm, 0, 2 * (size_t)n * sizeof(float), stream);   // outd + cnt
  k_cnt2<<<cdiv_i(E, 1024), 256, 0, stream>>>(src, dst, outnorm, cnt, rank, E);
  k_scan_a<<<nb, SCAN_B, 0, stream>>>(cnt, bsum, outnorm, innorm, invind, n);
  k_scan_b<<<1, 512, 0, stream>>>(bsum, nb, rowptr + n, E);
  k_scan_c<<<nb, SCAN_B, 0, stream>>>(cnt, bsum, rowptr, n);
  k_fill2<<<cdiv_i(E, 1024), 256, 0, stream>>>(src, dst, rowptr, rank, csr, E);

  // ---- fused encoder + layer-0 conv ----
  k_enc<<<nt, 256, 0, stream>>>(features, encW1, encb1, encW2, encb2, encW3, encb3,
                                W0, outnorm, hw_bf, n);
  k_gather_stats<<<GS_BLOCKS, 256, 0, stream>>>(hw_bf, rowptr, csr, innorm, b0, agg, p1, p2, n);
  k_bnred<<<128, 256, 0, stream>>>(p1, p2, bnsum, bnsq);
  k_post<<<cdiv_i(n * 16, 256), 256, 0, stream>>>(agg, innorm, b0, bnsum, bnsq, gamma, beta, inv_n,
                                                  nullptr, hbuf, h_bf, n * 16);

  // ---- layers 1..3 ----
  for (int i = 1; i < 4; ++i){
    const float* Wi = Wrest + (size_t)(i - 1) * 64 * 64;
    const float* bi = brest + (size_t)(i - 1) * 64;
    k_gather_nb<<<cdiv_i(n, 4), 256, 0, stream>>>(h_bf, rowptr, csr, nb_bf, n);
    k_attconv<<<nt, 256, 0, stream>>>(hbuf, nb_bf, invind, outnorm,
                                      attW1, attb1, attW2, attb2, Wi, hw_bf, n);
    k_gather_stats<<<GS_BLOCKS, 256, 0, stream>>>(hw_bf, rowptr, csr, innorm, bi, agg, p1, p2, n);
    k_bnred<<<128, 256, 0, stream>>>(p1, p2, bnsum + i * 64, bnsq + i * 64);
    if (i < 3){
      k_post<<<cdiv_i(n * 16, 256), 256, 0, stream>>>(agg, innorm, bi, bnsum + i * 64, bnsq + i * 64,
                                                      gamma + i * 64, beta + i * 64, inv_n,
                                                      hbuf, hbuf, h_bf, n * 16);
    } else {
      k_postfc<<<nt, 256, 0, stream>>>(agg, innorm, bi, bnsum + i * 64, bnsq + i * 64,
                                       gamma + i * 64, beta + i * 64, inv_n,
                                       hbuf, fcW, fcb, out, n);
    }
  }
}